// Round 8
// baseline (90.345 us; speedup 1.0000x reference)
//
#include <hip/hip_runtime.h>
#include <hip/hip_bf16.h>
#include <math.h>

#define BN 32
#define L 128
#define D 128
#define TT 127
#define NH 8

typedef float f32x4 __attribute__((ext_vector_type(4)));
typedef short s16x8 __attribute__((ext_vector_type(8)));

__device__ __forceinline__ float gelu_sig(float x) {
    // x * sigmoid(1.702x); |err vs erf-gelu| <= ~0.021 -> ~3e-3 at outputs
    float e = __expf(-1.702f * x);
    return x * __builtin_amdgcn_rcpf(1.0f + e);
}
__device__ __forceinline__ unsigned short f2bf(float f) {
    unsigned u = __float_as_uint(f);
    return (unsigned short)((u + 0x7fffu + ((u >> 16) & 1u)) >> 16);
}

// ---------------- K1: QKV projection (+ weight prepack in block 0,0,0) ----------------
__global__ __launch_bounds__(256)
void qkv_kernel(const float* __restrict__ padded, const float* __restrict__ tok,
                const float* __restrict__ Wq, const float* __restrict__ bq,
                const float* __restrict__ Wk, const float* __restrict__ bk,
                const float* __restrict__ Wv, const float* __restrict__ bv,
                const float* __restrict__ Wb1, const float* __restrict__ bb1,
                const float* __restrict__ Wb2,
                const float* __restrict__ Wv1, const float* __restrict__ bv1,
                const float* __restrict__ Wv2,
                float* __restrict__ Qo, float* __restrict__ Ko, float* __restrict__ Vo,
                float* __restrict__ CW, float* __restrict__ RVW,
                unsigned short* __restrict__ WV2F) {
    const int s = blockIdx.x;
    const int mat = blockIdx.y;
    const int chunk = blockIdx.z;
    const float* W = (mat == 0) ? Wq : (mat == 1) ? Wk : Wv;
    const float* bias = (mat == 0) ? bq : (mat == 1) ? bk : bv;
    float* outp = (mat == 0) ? Qo : (mat == 1) ? Ko : Vo;

    __shared__ float x_tile[32][D];
    const int tid = threadIdx.x;
    for (int idx = tid; idx < 32 * D; idx += 256) {
        int r = idx >> 7, c = idx & 127;
        int i = chunk * 32 + r;
        x_tile[r][c] = (i == 0) ? tok[c] : padded[(size_t)s * TT * D + (size_t)(i - 1) * D + c];
    }
    __syncthreads();

    const int c = tid & 127;
    const int rg = tid >> 7;
    const int r0 = rg * 16;
    float acc[16];
    const float bc = bias[c];
#pragma unroll
    for (int r = 0; r < 16; ++r) acc[r] = bc;
    for (int d = 0; d < D; ++d) {
        float wv = W[d * D + c];
#pragma unroll
        for (int r = 0; r < 16; ++r) acc[r] = fmaf(x_tile[r0 + r][d], wv, acc[r]);
    }
    size_t base = (size_t)s * L * D;
    for (int r = 0; r < 16; ++r)
        outp[base + (size_t)(chunk * 32 + r0 + r) * D + c] = acc[r];

    // ---- weight prepack (one block only; stream-serialized before K2/K3) ----
    if (s == 0 && mat == 0 && chunk == 0) {
        if (tid < 64) {
            const int u = tid;
            CW[u * 16 + 0] = Wb1[0 * 64 + u];
            CW[u * 16 + 1] = Wb1[1 * 64 + u];
            CW[u * 16 + 2] = Wb1[2 * 64 + u];
            CW[u * 16 + 3] = Wb1[3 * 64 + u] + Wb1[4 * 64 + u];
            CW[u * 16 + 4] = Wb1[5 * 64 + u];
            CW[u * 16 + 5] = bb1[u];
            CW[u * 16 + 6] = 0.f;
            CW[u * 16 + 7] = 0.f;
#pragma unroll
            for (int k = 0; k < 8; ++k) CW[u * 16 + 8 + k] = Wb2[u * 8 + k];
        }
        if (tid < 128) {
            const int cc = tid;
            RVW[cc * 8 + 0] = Wv1[0 * 128 + cc];
            RVW[cc * 8 + 1] = Wv1[1 * 128 + cc];
            RVW[cc * 8 + 2] = Wv1[2 * 128 + cc];
            RVW[cc * 8 + 3] = Wv1[3 * 128 + cc] + Wv1[4 * 128 + cc];
            RVW[cc * 8 + 4] = Wv1[5 * 128 + cc];
            RVW[cc * 8 + 5] = bv1[cc];
            RVW[cc * 8 + 6] = 0.f;
            RVW[cc * 8 + 7] = 0.f;
        }
        // Wv2 -> B-fragment order for mfma_f32_16x16x32_bf16
        for (int idx = tid; idx < 16384; idx += 256) {
            int f = idx >> 9, r = idx & 511, ln = r >> 3, e = r & 7;
            int kt = f >> 3, ng = f & 7;
            int row = kt * 32 + (ln >> 4) * 8 + e;
            int col = ng * 16 + (ln & 15);
            WV2F[idx] = f2bf(Wv2[(size_t)row * D + col]);
        }
    }
}

// ---------------- K2: logits via MFMA. grid (BN, NH), block 256 (4 waves) ----------------
__global__ __launch_bounds__(256)
void logits_kernel(const float* __restrict__ Q, const float* __restrict__ K,
                   __hip_bfloat16* __restrict__ LW) {
    const int s = blockIdx.x;
    const int h = blockIdx.y;
    const int tid = threadIdx.x;
    const int wv = tid >> 6;
    const int lane = tid & 63;
    const int lrn = lane & 15;
    const int kg = lane >> 4;

    __shared__ float Qs[128][16];
    __shared__ float Ks[128][16];
    for (int e = tid; e < 2048; e += 256) {
        int i = e >> 4, d = e & 15;
        Qs[i][d] = Q[((size_t)s * L + i) * D + h * 16 + d];
        Ks[i][d] = K[((size_t)s * L + i) * D + h * 16 + d];
    }
    __syncthreads();

    s16x8 afr[2];
#pragma unroll
    for (int m = 0; m < 2; ++m) {
        s16x8 a;
#pragma unroll
        for (int e = 0; e < 8; ++e) a[e] = 0;
        if (kg < 2) {
            const int i = wv * 32 + m * 16 + lrn;
            float4 q0 = *(const float4*)&Qs[i][kg * 8];
            float4 q1 = *(const float4*)&Qs[i][kg * 8 + 4];
            a[0] = (short)f2bf(q0.x); a[1] = (short)f2bf(q0.y);
            a[2] = (short)f2bf(q0.z); a[3] = (short)f2bf(q0.w);
            a[4] = (short)f2bf(q1.x); a[5] = (short)f2bf(q1.y);
            a[6] = (short)f2bf(q1.z); a[7] = (short)f2bf(q1.w);
        }
        afr[m] = a;
    }

    __hip_bfloat16* lw = LW + ((size_t)(s * NH + h) * L) * L;
#pragma unroll
    for (int n = 0; n < 8; ++n) {
        s16x8 b;
#pragma unroll
        for (int e = 0; e < 8; ++e) b[e] = 0;
        if (kg < 2) {
            const int j = n * 16 + lrn;
            float4 k0 = *(const float4*)&Ks[j][kg * 8];
            float4 k1 = *(const float4*)&Ks[j][kg * 8 + 4];
            b[0] = (short)f2bf(k0.x); b[1] = (short)f2bf(k0.y);
            b[2] = (short)f2bf(k0.z); b[3] = (short)f2bf(k0.w);
            b[4] = (short)f2bf(k1.x); b[5] = (short)f2bf(k1.y);
            b[6] = (short)f2bf(k1.z); b[7] = (short)f2bf(k1.w);
        }
#pragma unroll
        for (int m = 0; m < 2; ++m) {
            f32x4 acc = (f32x4){0.f, 0.f, 0.f, 0.f};
            acc = __builtin_amdgcn_mfma_f32_16x16x32_bf16(afr[m], b, acc, 0, 0, 0);
#pragma unroll
            for (int r = 0; r < 4; ++r)
                lw[(size_t)(wv * 32 + m * 16 + kg * 4 + r) * L + n * 16 + lrn] =
                    __float2bfloat16(acc[r] * 0.25f);
        }
    }
}

// ---------------- K2b: rel-bias MLP, added into LW. grid 2048, block 256 ----------------
// Thread <-> pair (s,i,j). Pure streaming, no LDS/barriers: runs at high VALU
// efficiency instead of serializing inside K3's critical path.
__global__ __launch_bounds__(256)
void bias_kernel(const float* __restrict__ pos3d, const float* __restrict__ CW,
                 const float* __restrict__ bb2, __hip_bfloat16* __restrict__ LW) {
    const int bid = blockIdx.x;
    const int s = bid >> 6;
    const int pair = (bid & 63) * 256 + threadIdx.x;
    const int i = pair >> 7;
    const int j = pair & 127;
    if (i == 0 || j == 0) return;   // bias row/col 0 are zeroed in the reference

    const float* pi = pos3d + ((size_t)s * TT + (i - 1)) * 3;
    const float* pj = pos3d + ((size_t)s * TT + (j - 1)) * 3;
    const float dx = pi[0] - pj[0], dy = pi[1] - pj[1], dz = pi[2] - pj[2];
    const float dist2 = dx * dx + dy * dy + dz * dz;
    const float dist = sqrtf(dist2);

    float bias[NH];
#pragma unroll
    for (int hh = 0; hh < NH; ++hh) bias[hh] = 0.f;
    const float4* cw4 = (const float4*)CW;
#pragma unroll 2
    for (int u = 0; u < 64; ++u) {
        float4 wa  = cw4[u * 4 + 0];
        float4 wb  = cw4[u * 4 + 1];
        float4 w2a = cw4[u * 4 + 2];
        float4 w2b = cw4[u * 4 + 3];
        float hv = wb.y;
        hv = fmaf(dx, wa.x, hv);
        hv = fmaf(dy, wa.y, hv);
        hv = fmaf(dz, wa.z, hv);
        hv = fmaf(dist, wa.w, hv);
        hv = fmaf(dist2, wb.x, hv);
        hv = gelu_sig(hv);
        bias[0] = fmaf(hv, w2a.x, bias[0]);
        bias[1] = fmaf(hv, w2a.y, bias[1]);
        bias[2] = fmaf(hv, w2a.z, bias[2]);
        bias[3] = fmaf(hv, w2a.w, bias[3]);
        bias[4] = fmaf(hv, w2b.x, bias[4]);
        bias[5] = fmaf(hv, w2b.y, bias[5]);
        bias[6] = fmaf(hv, w2b.z, bias[6]);
        bias[7] = fmaf(hv, w2b.w, bias[7]);
    }
#pragma unroll
    for (int hh = 0; hh < NH; ++hh) {
        const size_t o = ((size_t)(s * NH + hh) * L + i) * L + j;
        LW[o] = __float2bfloat16(__bfloat162float(LW[o]) + bias[hh] + bb2[hh]);
    }
}

// ---------------- K3: core per (s,i). grid (L, BN), block 128 (2 waves) ----------------
__global__ __launch_bounds__(128, 4)
void attn_kernel(const float* __restrict__ padded, const int* __restrict__ masks,
                 const float* __restrict__ pos3d,
                 const float* __restrict__ gamma, const float* __restrict__ beta,
                 const float* __restrict__ tok,
                 const float* __restrict__ RVW,
                 const unsigned short* __restrict__ WV2F,
                 const float* __restrict__ bv2,
                 const float* __restrict__ V, const __hip_bfloat16* __restrict__ LW,
                 float* __restrict__ out) {
    const int i = blockIdx.x;
    const int s = blockIdx.y;
    const int tid = threadIdx.x;
    const int wave = tid >> 6;
    const int lane = tid & 63;
    const int hA = lane & 15;        // mfma A-row / D-col index
    const int kg = lane >> 4;        // mfma k-group

    __shared__ float4 feat4_lds[144];          // idx j + (j>>3): {dx,dy,dz,dist}
    __shared__ float  feat5_lds[L];            // dist2
    __shared__ unsigned short w_bf[NH][136];   // COMPACTED softmax weights (bf16)
    __shared__ unsigned short gs_bf[NH][136];  // GS rows (bf16)
    __shared__ float  a1_part[4][132];
    __shared__ float  a2_lds[D];
    __shared__ float  reds[2][NH];
    __shared__ float  red2[2][2];
    __shared__ unsigned long long kb_lds[2];
    __shared__ int    jmap_lds[128];

    // ---- early loads: bias-added logits + mask ----
    __hip_bfloat16 lr8[NH];
#pragma unroll
    for (int hh = 0; hh < NH; ++hh)
        lr8[hh] = LW[((size_t)(s * NH + hh) * L + i) * L + tid];
    const int keep = (tid == 0) ? 1 : masks[(size_t)s * TT + (tid - 1)];

    const unsigned long long bal = __ballot(keep != 0);
    if (lane == 0) kb_lds[wave] = bal;

    // ---- relative features for pair (i, j=tid) ----
    float pix = 0.f, piy = 0.f, piz = 0.f;
    if (i > 0) { const float* pp = pos3d + ((size_t)s * TT + (i - 1)) * 3; pix = pp[0]; piy = pp[1]; piz = pp[2]; }
    float pjx = 0.f, pjy = 0.f, pjz = 0.f;
    if (tid > 0) { const float* pp = pos3d + ((size_t)s * TT + (tid - 1)) * 3; pjx = pp[0]; pjy = pp[1]; pjz = pp[2]; }
    const float dx = pix - pjx, dy = piy - pjy, dz = piz - pjz;
    const float dist2 = dx * dx + dy * dy + dz * dz;
    const float dist = sqrtf(dist2);
    feat4_lds[tid + (tid >> 3)] = make_float4(dx, dy, dz, dist);
    feat5_lds[tid] = dist2;

    // zero compacted-w array + jmap
    for (int idx = tid; idx < NH * 68; idx += 128) ((unsigned*)w_bf)[idx] = 0u;
    jmap_lds[tid] = 0;
    __syncthreads();                       // barrier A

    const unsigned long long b0 = kb_lds[0];
    const int nk = __popcll(b0) + __popcll(kb_lds[1]);
    const int NK32 = (nk + 31) >> 5;       // compacted 32-tiles (1..4)
    int rank = 0;
    if (keep) {
        rank = __popcll(bal & ((1ull << lane) - 1)) + (wave ? __popcll(b0) : 0);
        jmap_lds[rank] = tid;
    }

    // ---- softmax (bias already folded into LW by K2b) ----
    float p[NH];
#pragma unroll
    for (int hh = 0; hh < NH; ++hh) {
        float lv = __bfloat162float(lr8[hh]);
        p[hh] = keep ? __expf(lv) : 0.f;
    }
#pragma unroll
    for (int hh = 0; hh < NH; ++hh) {
        float v = p[hh];
        for (int off = 32; off >= 1; off >>= 1) v += __shfl_xor(v, off, 64);
        if (lane == 0) reds[wave][hh] = v;
    }
    __syncthreads();                       // barrier B
    if (keep) {
#pragma unroll
        for (int hh = 0; hh < NH; ++hh) {
            float inv = __builtin_amdgcn_rcpf(reds[0][hh] + reds[1][hh]);
            w_bf[hh][rank] = f2bf(p[hh] * inv);
        }
    }
    __syncthreads();                       // barrier C

    // ---- pass 2 ----
    const int jg = tid >> 5;
    const int c0v = (tid & 31) * 4;
    const int h0v = c0v >> 4;
    const int per = NK32 * 8;
    const float* Vs = V + (size_t)s * L * D;

    if (i > 0) {
        float rvw[4][6];
#pragma unroll
        for (int n = 0; n < 4; ++n) {
            const int c = wave * 64 + n * 16 + hA;
            float4 ra = *(const float4*)&RVW[(size_t)c * 8 + 0];
            rvw[n][0] = ra.x; rvw[n][1] = ra.y; rvw[n][2] = ra.z; rvw[n][3] = ra.w;
            rvw[n][4] = RVW[(size_t)c * 8 + 4];
            rvw[n][5] = RVW[(size_t)c * 8 + 5];
        }

        f32x4 accG[4];
#pragma unroll
        for (int n = 0; n < 4; ++n) accG[n] = (f32x4){0.f, 0.f, 0.f, 0.f};

        // ---- compacted G + GS via MFMA (NK32 k-tiles) ----
#pragma unroll
        for (int kt = 0; kt < 4; ++kt) {
            if (kt >= NK32) break;
            s16x8 wf;
#pragma unroll
            for (int e = 0; e < 8; ++e) wf[e] = 0;
            if (hA < NH) {
                wf = *(const s16x8*)&w_bf[hA][kt * 32 + kg * 8];
                if (kt == 0 && kg == 0) wf[0] = 0;   // exclude j==0 (rank 0) from g-sum
            }
            s16x8 bfr[4];
#pragma unroll
            for (int e = 0; e < 8; ++e) {
                const int jj = jmap_lds[kt * 32 + kg * 8 + e];
                float4 fa = feat4_lds[jj + (jj >> 3)];
                float f5 = feat5_lds[jj];
#pragma unroll
                for (int n = 0; n < 4; ++n) {
                    float hv = rvw[n][5];
                    hv = fmaf(fa.x, rvw[n][0], hv);
                    hv = fmaf(fa.y, rvw[n][1], hv);
                    hv = fmaf(fa.z, rvw[n][2], hv);
                    hv = fmaf(fa.w, rvw[n][3], hv);
                    hv = fmaf(f5,  rvw[n][4], hv);
                    bfr[n][e] = (short)f2bf(gelu_sig(hv));
                }
            }
#pragma unroll
            for (int n = 0; n < 4; ++n)
                accG[n] = __builtin_amdgcn_mfma_f32_16x16x32_bf16(wf, bfr[n], accG[n], 0, 0, 0);
        }

        // ---- a1 over compacted keys ----
        float a1a[4] = {0.f, 0.f, 0.f, 0.f};
        for (int r = 0; r < per; ++r) {
            const int jt = jg * per + r;
            const int jr = jmap_lds[jt];
            float4 vcur = *(const float4*)&Vs[(size_t)jr * D + c0v];
            const float wj = __uint_as_float((unsigned)w_bf[h0v][jt] << 16);
            a1a[0] = fmaf(wj, vcur.x, a1a[0]);
            a1a[1] = fmaf(wj, vcur.y, a1a[1]);
            a1a[2] = fmaf(wj, vcur.z, a1a[2]);
            a1a[3] = fmaf(wj, vcur.w, a1a[3]);
        }
        *(float4*)&a1_part[jg][c0v] = make_float4(a1a[0], a1a[1], a1a[2], a1a[3]);

        // GS rows 0..7 live in lanes 0..31 (D-layout row=(lane>>4)*4+reg)
        if (lane < 32) {
#pragma unroll
            for (int n = 0; n < 4; ++n)
#pragma unroll
                for (int r = 0; r < 4; ++r)
                    gs_bf[(lane >> 4) * 4 + r][wave * 64 + n * 16 + hA] = f2bf(accG[n][r]);
        }
        __syncthreads();

        // ---- a2 = GS @ Wv2 via MFMA (B prepacked in WV2F) ----
        f32x4 acc2[4];
#pragma unroll
        for (int n = 0; n < 4; ++n) acc2[n] = (f32x4){0.f, 0.f, 0.f, 0.f};
#pragma unroll
        for (int kt = 0; kt < 4; ++kt) {
            s16x8 gf;
#pragma unroll
            for (int e = 0; e < 8; ++e) gf[e] = 0;
            if (hA < NH)
                gf = *(const s16x8*)&gs_bf[hA][kt * 32 + kg * 8];
#pragma unroll
            for (int n = 0; n < 4; ++n) {
                const int f = kt * 8 + wave * 4 + n;
                s16x8 bw = *(const s16x8*)&WV2F[((size_t)f * 64 + lane) * 8];
                acc2[n] = __builtin_amdgcn_mfma_f32_16x16x32_bf16(gf, bw, acc2[n], 0, 0, 0);
            }
        }
#pragma unroll
        for (int n = 0; n < 4; ++n)
            if (kg == wave) a2_lds[wave * 64 + n * 16 + hA] = acc2[n][n];
        __syncthreads();

        // ---- epilogue ----
        const float a1f = a1_part[0][tid] + a1_part[1][tid] + a1_part[2][tid] + a1_part[3][tid];
        const float S1 = 1.0f - __uint_as_float((unsigned)w_bf[tid >> 4][0] << 16);
        const size_t o = (size_t)s * TT * D + (size_t)(i - 1) * D + tid;
        out[o] = a1f + a2_lds[tid] + S1 * bv2[tid] + padded[o];
    } else {
        // ---- cls row: a2 == 0; V-reduce (compacted) + layernorm ----
        float a1a[4] = {0.f, 0.f, 0.f, 0.f};
        for (int r = 0; r < per; ++r) {
            const int jt = jg * per + r;
            const int jr = jmap_lds[jt];
            float4 vcur = *(const float4*)&Vs[(size_t)jr * D + c0v];
            const float wj = __uint_as_float((unsigned)w_bf[h0v][jt] << 16);
            a1a[0] = fmaf(wj, vcur.x, a1a[0]);
            a1a[1] = fmaf(wj, vcur.y, a1a[1]);
            a1a[2] = fmaf(wj, vcur.z, a1a[2]);
            a1a[3] = fmaf(wj, vcur.w, a1a[3]);
        }
        *(float4*)&a1_part[jg][c0v] = make_float4(a1a[0], a1a[1], a1a[2], a1a[3]);
        __syncthreads();
        const float a1f = a1_part[0][tid] + a1_part[1][tid] + a1_part[2][tid] + a1_part[3][tid];

        float st = a1f + tok[tid];
        float sum = st, sum2 = st * st;
        for (int off = 32; off >= 1; off >>= 1) {
            sum += __shfl_xor(sum, off, 64);
            sum2 += __shfl_xor(sum2, off, 64);
        }
        if (lane == 0) { red2[wave][0] = sum; red2[wave][1] = sum2; }
        __syncthreads();
        sum = red2[0][0] + red2[1][0];
        sum2 = red2[0][1] + red2[1][1];
        const float mu = sum * (1.0f / 128.0f);
        const float var = sum2 * (1.0f / 128.0f) - mu * mu;
        const float y = (st - mu) * rsqrtf(var + 1e-5f) * gamma[tid] + beta[tid];
        out[(size_t)BN * TT * D + (size_t)s * D + tid] = y;
    }
}

extern "C" void kernel_launch(void* const* d_in, const int* in_sizes, int n_in,
                              void* d_out, int out_size, void* d_ws, size_t ws_size,
                              hipStream_t stream) {
    const float* padded = (const float*)d_in[0];
    const int*   masks  = (const int*)d_in[1];
    const float* pos3d  = (const float*)d_in[2];
    const float* Wq = (const float*)d_in[3];
    const float* bq = (const float*)d_in[4];
    const float* Wk = (const float*)d_in[5];
    const float* bk = (const float*)d_in[6];
    const float* Wv = (const float*)d_in[7];
    const float* bv = (const float*)d_in[8];
    const float* gamma = (const float*)d_in[9];
    const float* beta  = (const float*)d_in[10];
    const float* tok   = (const float*)d_in[11];
    const float* Wb1 = (const float*)d_in[12];
    const float* bb1 = (const float*)d_in[13];
    const float* Wb2 = (const float*)d_in[14];
    const float* bb2 = (const float*)d_in[15];
    const float* Wv1 = (const float*)d_in[16];
    const float* bv1 = (const float*)d_in[17];
    const float* Wv2 = (const float*)d_in[18];
    const float* bv2 = (const float*)d_in[19];
    float* out = (float*)d_out;

    float* Q  = (float*)d_ws;
    float* K  = Q + (size_t)BN * L * D;
    float* Vw = K + (size_t)BN * L * D;
    __hip_bfloat16* LW = (__hip_bfloat16*)(Vw + (size_t)BN * L * D);
    float* CW  = (float*)(LW + (size_t)BN * NH * L * L);
    float* RVW = CW + 64 * 16;
    unsigned short* WV2F = (unsigned short*)(RVW + 128 * 8);

    qkv_kernel<<<dim3(BN, 3, 4), 256, 0, stream>>>(padded, tok, Wq, bq, Wk, bk, Wv, bv,
                                                   Wb1, bb1, Wb2, Wv1, bv1, Wv2,
                                                   Q, K, Vw, CW, RVW, WV2F);
    logits_kernel<<<dim3(BN, NH), 256, 0, stream>>>(Q, K, LW);
    bias_kernel<<<dim3(2048), 256, 0, stream>>>(pos3d, CW, bb2, LW);
    attn_kernel<<<dim3(L, BN), 128, 0, stream>>>(padded, masks, pos3d, gamma, beta, tok,
                                                 RVW, WV2F, bv2,
                                                 Vw, LW, out);
}

// Round 9
// 82.862 us; speedup vs baseline: 1.0903x; 1.0903x over previous
//
#include <hip/hip_runtime.h>
#include <hip/hip_bf16.h>
#include <math.h>

#define BN 32
#define L 128
#define D 128
#define TT 127
#define NH 8

typedef float f32x4 __attribute__((ext_vector_type(4)));
typedef short s16x8 __attribute__((ext_vector_type(8)));

__device__ __forceinline__ float gelu_sig(float x) {
    float e = __expf(-1.702f * x);
    return x * __builtin_amdgcn_rcpf(1.0f + e);
}
__device__ __forceinline__ unsigned short f2bf(float f) {
    unsigned u = __float_as_uint(f);
    return (unsigned short)((u + 0x7fffu + ((u >> 16) & 1u)) >> 16);
}
__device__ __forceinline__ float bf2f(unsigned short v) {
    return __uint_as_float((unsigned)v << 16);
}

// ---------------- K1: QKV projection via MFMA. grid (BN,3,4), block 256 ----------------
__global__ __launch_bounds__(256)
void qkv_kernel(const float* __restrict__ padded, const float* __restrict__ tok,
                const float* __restrict__ Wq, const float* __restrict__ bq,
                const float* __restrict__ Wk, const float* __restrict__ bk,
                const float* __restrict__ Wv, const float* __restrict__ bv,
                const float* __restrict__ Wb1, const float* __restrict__ bb1,
                const float* __restrict__ Wb2,
                const float* __restrict__ Wv1, const float* __restrict__ bv1,
                const float* __restrict__ Wv2,
                float* __restrict__ Qo, float* __restrict__ Ko, float* __restrict__ Vo,
                float* __restrict__ CW, float* __restrict__ RVW,
                unsigned short* __restrict__ WV2F) {
    const int s = blockIdx.x;
    const int mat = blockIdx.y;
    const int chunk = blockIdx.z;
    const float* W = (mat == 0) ? Wq : (mat == 1) ? Wk : Wv;
    const float* bias = (mat == 0) ? bq : (mat == 1) ? bk : bv;
    float* outp = (mat == 0) ? Qo : (mat == 1) ? Ko : Vo;

    __shared__ unsigned short Xs[32][136];   // bf16 X chunk (32 rows x 128)
    const int tid = threadIdx.x;

    // ---- stage 32 rows of X as bf16 ----
    {
        const int row = tid >> 3;
        const int colbase = (tid & 7) * 16;
        const int i = chunk * 32 + row;
        const float* src = (i == 0) ? tok : &padded[(size_t)s * TT * D + (size_t)(i - 1) * D];
#pragma unroll
        for (int k4 = 0; k4 < 4; ++k4) {
            float4 v = *(const float4*)&src[colbase + k4 * 4];
            unsigned lo = (unsigned)f2bf(v.x) | ((unsigned)f2bf(v.y) << 16);
            unsigned hi = (unsigned)f2bf(v.z) | ((unsigned)f2bf(v.w) << 16);
            *(uint2*)&Xs[row][colbase + k4 * 4] = make_uint2(lo, hi);
        }
    }
    __syncthreads();

    const int wave = tid >> 6;
    const int lane = tid & 63;
    const int hA = lane & 15;
    const int kg = lane >> 4;

    // A-fragments from LDS
    s16x8 afr[2][4];
#pragma unroll
    for (int m = 0; m < 2; ++m)
#pragma unroll
        for (int kt = 0; kt < 4; ++kt)
            afr[m][kt] = *(const s16x8*)&Xs[m * 16 + hA][kt * 32 + kg * 8];

    f32x4 acc[2][2];
#pragma unroll
    for (int m = 0; m < 2; ++m)
#pragma unroll
        for (int n = 0; n < 2; ++n) acc[m][n] = (f32x4){0.f, 0.f, 0.f, 0.f};

#pragma unroll
    for (int kt = 0; kt < 4; ++kt) {
#pragma unroll
        for (int n = 0; n < 2; ++n) {
            const int col = (2 * wave + n) * 16 + hA;
            s16x8 bw;
#pragma unroll
            for (int e = 0; e < 8; ++e)
                bw[e] = (short)f2bf(W[(size_t)(kt * 32 + kg * 8 + e) * D + col]);
            acc[0][n] = __builtin_amdgcn_mfma_f32_16x16x32_bf16(afr[0][kt], bw, acc[0][n], 0, 0, 0);
            acc[1][n] = __builtin_amdgcn_mfma_f32_16x16x32_bf16(afr[1][kt], bw, acc[1][n], 0, 0, 0);
        }
    }

#pragma unroll
    for (int n = 0; n < 2; ++n) {
        const int col = (2 * wave + n) * 16 + hA;
        const float bc = bias[col];
#pragma unroll
        for (int m = 0; m < 2; ++m)
#pragma unroll
            for (int r = 0; r < 4; ++r) {
                const int row = chunk * 32 + m * 16 + kg * 4 + r;
                outp[(size_t)s * L * D + (size_t)row * D + col] = acc[m][n][r] + bc;
            }
    }

    // ---- weight prepack (one block only; stream-serialized before K2b/K3) ----
    if (s == 0 && mat == 0 && chunk == 0) {
        if (tid < 64) {
            const int u = tid;
            CW[u * 16 + 0] = Wb1[0 * 64 + u];
            CW[u * 16 + 1] = Wb1[1 * 64 + u];
            CW[u * 16 + 2] = Wb1[2 * 64 + u];
            CW[u * 16 + 3] = Wb1[3 * 64 + u] + Wb1[4 * 64 + u];
            CW[u * 16 + 4] = Wb1[5 * 64 + u];
            CW[u * 16 + 5] = bb1[u];
            CW[u * 16 + 6] = 0.f;
            CW[u * 16 + 7] = 0.f;
#pragma unroll
            for (int k = 0; k < 8; ++k) CW[u * 16 + 8 + k] = Wb2[u * 8 + k];
        }
        if (tid < 128) {
            const int cc = tid;
            RVW[cc * 8 + 0] = Wv1[0 * 128 + cc];
            RVW[cc * 8 + 1] = Wv1[1 * 128 + cc];
            RVW[cc * 8 + 2] = Wv1[2 * 128 + cc];
            RVW[cc * 8 + 3] = Wv1[3 * 128 + cc] + Wv1[4 * 128 + cc];
            RVW[cc * 8 + 4] = Wv1[5 * 128 + cc];
            RVW[cc * 8 + 5] = bv1[cc];
            RVW[cc * 8 + 6] = 0.f;
            RVW[cc * 8 + 7] = 0.f;
        }
        for (int idx = tid; idx < 16384; idx += 256) {
            int f = idx >> 9, r = idx & 511, ln = r >> 3, e = r & 7;
            int kt = f >> 3, ng = f & 7;
            int row = kt * 32 + (ln >> 4) * 8 + e;
            int col = ng * 16 + (ln & 15);
            WV2F[idx] = f2bf(Wv2[(size_t)row * D + col]);
        }
    }
}

// ---------------- K2: logits via MFMA. grid (BN, NH), block 256 (4 waves) ----------------
__global__ __launch_bounds__(256)
void logits_kernel(const float* __restrict__ Q, const float* __restrict__ K,
                   __hip_bfloat16* __restrict__ LW) {
    const int s = blockIdx.x;
    const int h = blockIdx.y;
    const int tid = threadIdx.x;
    const int wv = tid >> 6;
    const int lane = tid & 63;
    const int lrn = lane & 15;
    const int kg = lane >> 4;

    __shared__ float Qs[128][16];
    __shared__ float Ks[128][16];
    for (int e = tid; e < 2048; e += 256) {
        int i = e >> 4, d = e & 15;
        Qs[i][d] = Q[((size_t)s * L + i) * D + h * 16 + d];
        Ks[i][d] = K[((size_t)s * L + i) * D + h * 16 + d];
    }
    __syncthreads();

    s16x8 afr[2];
#pragma unroll
    for (int m = 0; m < 2; ++m) {
        s16x8 a;
#pragma unroll
        for (int e = 0; e < 8; ++e) a[e] = 0;
        if (kg < 2) {
            const int i = wv * 32 + m * 16 + lrn;
            float4 q0 = *(const float4*)&Qs[i][kg * 8];
            float4 q1 = *(const float4*)&Qs[i][kg * 8 + 4];
            a[0] = (short)f2bf(q0.x); a[1] = (short)f2bf(q0.y);
            a[2] = (short)f2bf(q0.z); a[3] = (short)f2bf(q0.w);
            a[4] = (short)f2bf(q1.x); a[5] = (short)f2bf(q1.y);
            a[6] = (short)f2bf(q1.z); a[7] = (short)f2bf(q1.w);
        }
        afr[m] = a;
    }

    __hip_bfloat16* lw = LW + ((size_t)(s * NH + h) * L) * L;
#pragma unroll
    for (int n = 0; n < 8; ++n) {
        s16x8 b;
#pragma unroll
        for (int e = 0; e < 8; ++e) b[e] = 0;
        if (kg < 2) {
            const int j = n * 16 + lrn;
            float4 k0 = *(const float4*)&Ks[j][kg * 8];
            float4 k1 = *(const float4*)&Ks[j][kg * 8 + 4];
            b[0] = (short)f2bf(k0.x); b[1] = (short)f2bf(k0.y);
            b[2] = (short)f2bf(k0.z); b[3] = (short)f2bf(k0.w);
            b[4] = (short)f2bf(k1.x); b[5] = (short)f2bf(k1.y);
            b[6] = (short)f2bf(k1.z); b[7] = (short)f2bf(k1.w);
        }
#pragma unroll
        for (int m = 0; m < 2; ++m) {
            f32x4 acc = (f32x4){0.f, 0.f, 0.f, 0.f};
            acc = __builtin_amdgcn_mfma_f32_16x16x32_bf16(afr[m], b, acc, 0, 0, 0);
#pragma unroll
            for (int r = 0; r < 4; ++r)
                lw[(size_t)(wv * 32 + m * 16 + kg * 4 + r) * L + n * 16 + lrn] =
                    __float2bfloat16(acc[r] * 0.25f);
        }
    }
}

// ---------------- K2b: rel-bias MLP, added into LW. grid 2048, block 256 ----------------
__global__ __launch_bounds__(256)
void bias_kernel(const float* __restrict__ pos3d, const float* __restrict__ CW,
                 const float* __restrict__ bb2, __hip_bfloat16* __restrict__ LW) {
    const int bid = blockIdx.x;
    const int s = bid >> 6;
    const int pair = (bid & 63) * 256 + threadIdx.x;
    const int i = pair >> 7;
    const int j = pair & 127;
    if (i == 0 || j == 0) return;

    const float* pi = pos3d + ((size_t)s * TT + (i - 1)) * 3;
    const float* pj = pos3d + ((size_t)s * TT + (j - 1)) * 3;
    const float dx = pi[0] - pj[0], dy = pi[1] - pj[1], dz = pi[2] - pj[2];
    const float dist2 = dx * dx + dy * dy + dz * dz;
    const float dist = sqrtf(dist2);

    float bias[NH];
#pragma unroll
    for (int hh = 0; hh < NH; ++hh) bias[hh] = 0.f;
    const float4* cw4 = (const float4*)CW;
#pragma unroll 2
    for (int u = 0; u < 64; ++u) {
        float4 wa  = cw4[u * 4 + 0];
        float4 wb  = cw4[u * 4 + 1];
        float4 w2a = cw4[u * 4 + 2];
        float4 w2b = cw4[u * 4 + 3];
        float hv = wb.y;
        hv = fmaf(dx, wa.x, hv);
        hv = fmaf(dy, wa.y, hv);
        hv = fmaf(dz, wa.z, hv);
        hv = fmaf(dist, wa.w, hv);
        hv = fmaf(dist2, wb.x, hv);
        hv = gelu_sig(hv);
        bias[0] = fmaf(hv, w2a.x, bias[0]);
        bias[1] = fmaf(hv, w2a.y, bias[1]);
        bias[2] = fmaf(hv, w2a.z, bias[2]);
        bias[3] = fmaf(hv, w2a.w, bias[3]);
        bias[4] = fmaf(hv, w2b.x, bias[4]);
        bias[5] = fmaf(hv, w2b.y, bias[5]);
        bias[6] = fmaf(hv, w2b.z, bias[6]);
        bias[7] = fmaf(hv, w2b.w, bias[7]);
    }
#pragma unroll
    for (int hh = 0; hh < NH; ++hh) {
        const size_t o = ((size_t)(s * NH + hh) * L + i) * L + j;
        LW[o] = __float2bfloat16(__bfloat162float(LW[o]) + bias[hh] + bb2[hh]);
    }
}

// ---------------- K3: core per (s,i). grid (L, BN), block 256 (4 waves) ----------------
__global__ __launch_bounds__(256, 4)
void attn_kernel(const float* __restrict__ padded, const int* __restrict__ masks,
                 const float* __restrict__ pos3d,
                 const float* __restrict__ gamma, const float* __restrict__ beta,
                 const float* __restrict__ tok,
                 const float* __restrict__ RVW,
                 const unsigned short* __restrict__ WV2F,
                 const float* __restrict__ bv2,
                 const float* __restrict__ V, const __hip_bfloat16* __restrict__ LW,
                 float* __restrict__ out) {
    const int i = blockIdx.x;
    const int s = blockIdx.y;
    const int tid = threadIdx.x;
    const int wave = tid >> 6;
    const int lane = tid & 63;
    const int hA = lane & 15;
    const int kg = lane >> 4;
    const int j = tid & 127;              // phase-1 key index (two thread-halves)
    const int hbase = (tid >> 7) * 4;     // heads 0-3 or 4-7

    __shared__ float4 feat4_lds[144];
    __shared__ float  feat5_lds[L];
    __shared__ unsigned short w_bf[NH][136];
    __shared__ unsigned short gs_bf[NH][136];
    __shared__ float  a1_part[8][132];
    __shared__ float  a2_lds[D];
    __shared__ float  reds[4][NH];
    __shared__ float  red2[2][2];
    __shared__ unsigned long long kb_lds[2];
    __shared__ int    jmap_lds[128];

    // ---- early loads: 4 heads' logits + mask ----
    __hip_bfloat16 lr4[4];
#pragma unroll
    for (int k = 0; k < 4; ++k)
        lr4[k] = LW[((size_t)(s * NH + hbase + k) * L + i) * L + j];
    const int keep = (j == 0) ? 1 : masks[(size_t)s * TT + (j - 1)];

    const unsigned long long bal = __ballot(keep != 0);
    if (lane == 0 && wave < 2) kb_lds[wave] = bal;

    // ---- relative features (threads 0-127) ----
    if (tid < 128) {
        float pix = 0.f, piy = 0.f, piz = 0.f;
        if (i > 0) { const float* pp = pos3d + ((size_t)s * TT + (i - 1)) * 3; pix = pp[0]; piy = pp[1]; piz = pp[2]; }
        float pjx = 0.f, pjy = 0.f, pjz = 0.f;
        if (tid > 0) { const float* pp = pos3d + ((size_t)s * TT + (tid - 1)) * 3; pjx = pp[0]; pjy = pp[1]; pjz = pp[2]; }
        const float dx = pix - pjx, dy = piy - pjy, dz = piz - pjz;
        const float dist2 = dx * dx + dy * dy + dz * dz;
        const float dist = sqrtf(dist2);
        feat4_lds[tid + (tid >> 3)] = make_float4(dx, dy, dz, dist);
        feat5_lds[tid] = dist2;
        jmap_lds[tid] = 0;
    }
    for (int idx = tid; idx < NH * 68; idx += 256) ((unsigned*)w_bf)[idx] = 0u;
    __syncthreads();                       // A

    const unsigned long long b0 = kb_lds[0];
    const int nk = __popcll(b0) + __popcll(kb_lds[1]);
    const int NK32 = (nk + 31) >> 5;
    int rank = 0;
    if (keep) {
        rank = __popcll(bal & ((1ull << lane) - 1)) + ((wave & 1) ? __popcll(b0) : 0);
        if (wave < 2) jmap_lds[rank] = j;
    }

    // ---- softmax: 4 heads per thread-half ----
    float p4[4];
#pragma unroll
    for (int k = 0; k < 4; ++k) {
        float lv = __bfloat162float(lr4[k]);
        p4[k] = keep ? __expf(lv) : 0.f;
    }
#pragma unroll
    for (int k = 0; k < 4; ++k) {
        float v = p4[k];
        for (int off = 32; off >= 1; off >>= 1) v += __shfl_xor(v, off, 64);
        if (lane == 0) reds[wave][hbase + k] = v;
    }
    __syncthreads();                       // B
    if (keep) {
        const int pb = (tid >> 7) * 2;
#pragma unroll
        for (int k = 0; k < 4; ++k) {
            const int hh = hbase + k;
            float inv = __builtin_amdgcn_rcpf(reds[pb][hh] + reds[pb + 1][hh]);
            w_bf[hh][rank] = f2bf(p4[k] * inv);
        }
    }
    __syncthreads();                       // C

    // ---- pass 2 ----
    const int jg = tid >> 5;               // 0..7
    const int c0v = (tid & 31) * 4;
    const int h0v = c0v >> 4;
    const int perg = NK32 * 4;             // a1 rows per jg group
    const float* Vs = V + (size_t)s * L * D;

    if (i > 0) {
        const int ng0 = 2 * wave;
        float rvw[2][6];
#pragma unroll
        for (int n = 0; n < 2; ++n) {
            const int c = (ng0 + n) * 16 + hA;
            float4 ra = *(const float4*)&RVW[(size_t)c * 8 + 0];
            rvw[n][0] = ra.x; rvw[n][1] = ra.y; rvw[n][2] = ra.z; rvw[n][3] = ra.w;
            rvw[n][4] = RVW[(size_t)c * 8 + 4];
            rvw[n][5] = RVW[(size_t)c * 8 + 5];
        }

        f32x4 accG[2];
#pragma unroll
        for (int n = 0; n < 2; ++n) accG[n] = (f32x4){0.f, 0.f, 0.f, 0.f};

#pragma unroll
        for (int kt = 0; kt < 4; ++kt) {
            if (kt >= NK32) break;
            s16x8 wf;
#pragma unroll
            for (int e = 0; e < 8; ++e) wf[e] = 0;
            if (hA < NH) {
                wf = *(const s16x8*)&w_bf[hA][kt * 32 + kg * 8];
                if (kt == 0 && kg == 0) wf[0] = 0;   // exclude j==0 (rank 0)
            }
            s16x8 bfr[2];
#pragma unroll
            for (int e = 0; e < 8; ++e) {
                const int jj = jmap_lds[kt * 32 + kg * 8 + e];
                float4 fa = feat4_lds[jj + (jj >> 3)];
                float f5 = feat5_lds[jj];
#pragma unroll
                for (int n = 0; n < 2; ++n) {
                    float hv = rvw[n][5];
                    hv = fmaf(fa.x, rvw[n][0], hv);
                    hv = fmaf(fa.y, rvw[n][1], hv);
                    hv = fmaf(fa.z, rvw[n][2], hv);
                    hv = fmaf(fa.w, rvw[n][3], hv);
                    hv = fmaf(f5,  rvw[n][4], hv);
                    bfr[n][e] = (short)f2bf(gelu_sig(hv));
                }
            }
#pragma unroll
            for (int n = 0; n < 2; ++n)
                accG[n] = __builtin_amdgcn_mfma_f32_16x16x32_bf16(wf, bfr[n], accG[n], 0, 0, 0);
        }

        // ---- a1 over compacted keys (8 groups) ----
        float a1a[4] = {0.f, 0.f, 0.f, 0.f};
        for (int r = 0; r < perg; ++r) {
            const int jt = jg * perg + r;
            const int jr = jmap_lds[jt];
            float4 vcur = *(const float4*)&Vs[(size_t)jr * D + c0v];
            const float wj = bf2f(w_bf[h0v][jt]);
            a1a[0] = fmaf(wj, vcur.x, a1a[0]);
            a1a[1] = fmaf(wj, vcur.y, a1a[1]);
            a1a[2] = fmaf(wj, vcur.z, a1a[2]);
            a1a[3] = fmaf(wj, vcur.w, a1a[3]);
        }
        *(float4*)&a1_part[jg][c0v] = make_float4(a1a[0], a1a[1], a1a[2], a1a[3]);

        if (lane < 32) {
#pragma unroll
            for (int n = 0; n < 2; ++n)
#pragma unroll
                for (int r = 0; r < 4; ++r)
                    gs_bf[(lane >> 4) * 4 + r][(ng0 + n) * 16 + hA] = f2bf(accG[n][r]);
        }
        __syncthreads();

        // ---- a2 = GS @ Wv2 via MFMA (2 col-frags per wave) ----
        f32x4 acc2[2];
#pragma unroll
        for (int n = 0; n < 2; ++n) acc2[n] = (f32x4){0.f, 0.f, 0.f, 0.f};
#pragma unroll
        for (int kt = 0; kt < 4; ++kt) {
            s16x8 gf;
#pragma unroll
            for (int e = 0; e < 8; ++e) gf[e] = 0;
            if (hA < NH)
                gf = *(const s16x8*)&gs_bf[hA][kt * 32 + kg * 8];
#pragma unroll
            for (int n = 0; n < 2; ++n) {
                const int f = kt * 8 + ng0 + n;
                s16x8 bw = *(const s16x8*)&WV2F[((size_t)f * 64 + lane) * 8];
                acc2[n] = __builtin_amdgcn_mfma_f32_16x16x32_bf16(gf, bw, acc2[n], 0, 0, 0);
            }
        }
#pragma unroll
        for (int n = 0; n < 2; ++n) {
            const int f = ng0 + n;
            if (kg == (f >> 2)) a2_lds[f * 16 + hA] = acc2[n][f & 3];
        }
        __syncthreads();

        if (tid < 128) {
            float a1f = a1_part[0][tid] + a1_part[1][tid] + a1_part[2][tid] + a1_part[3][tid]
                      + a1_part[4][tid] + a1_part[5][tid] + a1_part[6][tid] + a1_part[7][tid];
            const float S1 = 1.0f - bf2f(w_bf[tid >> 4][0]);
            const size_t o = (size_t)s * TT * D + (size_t)(i - 1) * D + tid;
            out[o] = a1f + a2_lds[tid] + S1 * bv2[tid] + padded[o];
        }
    } else {
        // ---- cls row: a2 == 0; V-reduce + layernorm ----
        float a1a[4] = {0.f, 0.f, 0.f, 0.f};
        for (int r = 0; r < perg; ++r) {
            const int jt = jg * perg + r;
            const int jr = jmap_lds[jt];
            float4 vcur = *(const float4*)&Vs[(size_t)jr * D + c0v];
            const float wj = bf2f(w_bf[h0v][jt]);
            a1a[0] = fmaf(wj, vcur.x, a1a[0]);
            a1a[1] = fmaf(wj, vcur.y, a1a[1]);
            a1a[2] = fmaf(wj, vcur.z, a1a[2]);
            a1a[3] = fmaf(wj, vcur.w, a1a[3]);
        }
        *(float4*)&a1_part[jg][c0v] = make_float4(a1a[0], a1a[1], a1a[2], a1a[3]);
        __syncthreads();

        float st = 0.f;
        if (tid < 128) {
            float a1f = a1_part[0][tid] + a1_part[1][tid] + a1_part[2][tid] + a1_part[3][tid]
                      + a1_part[4][tid] + a1_part[5][tid] + a1_part[6][tid] + a1_part[7][tid];
            st = a1f + tok[tid];
            float sum = st, sum2 = st * st;
            for (int off = 32; off >= 1; off >>= 1) {
                sum += __shfl_xor(sum, off, 64);
                sum2 += __shfl_xor(sum2, off, 64);
            }
            if (lane == 0) { red2[wave][0] = sum; red2[wave][1] = sum2; }
        }
        __syncthreads();
        if (tid < 128) {
            float sum = red2[0][0] + red2[1][0];
            float sum2 = red2[0][1] + red2[1][1];
            const float mu = sum * (1.0f / 128.0f);
            const float var = sum2 * (1.0f / 128.0f) - mu * mu;
            const float y = (st - mu) * rsqrtf(var + 1e-5f) * gamma[tid] + beta[tid];
            out[(size_t)BN * TT * D + (size_t)s * D + tid] = y;
        }
    }
}

extern "C" void kernel_launch(void* const* d_in, const int* in_sizes, int n_in,
                              void* d_out, int out_size, void* d_ws, size_t ws_size,
                              hipStream_t stream) {
    const float* padded = (const float*)d_in[0];
    const int*   masks  = (const int*)d_in[1];
    const float* pos3d  = (const float*)d_in[2];
    const float* Wq = (const float*)d_in[3];
    const float* bq = (const float*)d_in[4];
    const float* Wk = (const float*)d_in[5];
    const float* bk = (const float*)d_in[6];
    const float* Wv = (const float*)d_in[7];
    const float* bv = (const float*)d_in[8];
    const float* gamma = (const float*)d_in[9];
    const float* beta  = (const float*)d_in[10];
    const float* tok   = (const float*)d_in[11];
    const float* Wb1 = (const float*)d_in[12];
    const float* bb1 = (const float*)d_in[13];
    const float* Wb2 = (const float*)d_in[14];
    const float* bb2 = (const float*)d_in[15];
    const float* Wv1 = (const float*)d_in[16];
    const float* bv1 = (const float*)d_in[17];
    const float* Wv2 = (const float*)d_in[18];
    const float* bv2 = (const float*)d_in[19];
    float* out = (float*)d_out;

    float* Q  = (float*)d_ws;
    float* K  = Q + (size_t)BN * L * D;
    float* Vw = K + (size_t)BN * L * D;
    __hip_bfloat16* LW = (__hip_bfloat16*)(Vw + (size_t)BN * L * D);
    float* CW  = (float*)(LW + (size_t)BN * NH * L * L);
    float* RVW = CW + 64 * 16;
    unsigned short* WV2F = (unsigned short*)(RVW + 128 * 8);

    qkv_kernel<<<dim3(BN, 3, 4), 256, 0, stream>>>(padded, tok, Wq, bq, Wk, bk, Wv, bv,
                                                   Wb1, bb1, Wb2, Wv1, bv1, Wv2,
                                                   Q, K, Vw, CW, RVW, WV2F);
    logits_kernel<<<dim3(BN, NH), 256, 0, stream>>>(Q, K, LW);
    bias_kernel<<<dim3(2048), 256, 0, stream>>>(pos3d, CW, bb2, LW);
    attn_kernel<<<dim3(L, BN), 256, 0, stream>>>(padded, masks, pos3d, gamma, beta, tok,
                                                 RVW, WV2F, bv2,
                                                 Vw, LW, out);
}

// Round 10
// 79.099 us; speedup vs baseline: 1.1422x; 1.0476x over previous
//
#include <hip/hip_runtime.h>
#include <hip/hip_bf16.h>
#include <math.h>

#define BN 32
#define L 128
#define D 128
#define TT 127
#define NH 8

typedef float f32x4 __attribute__((ext_vector_type(4)));
typedef short s16x8 __attribute__((ext_vector_type(8)));

__device__ __forceinline__ float gelu_sig(float x) {
    float e = __expf(-1.702f * x);
    return x * __builtin_amdgcn_rcpf(1.0f + e);
}
__device__ __forceinline__ unsigned short f2bf(float f) {
    unsigned u = __float_as_uint(f);
    return (unsigned short)((u + 0x7fffu + ((u >> 16) & 1u)) >> 16);
}
__device__ __forceinline__ float bf2f(unsigned short v) {
    return __uint_as_float((unsigned)v << 16);
}

// ---------------- K1: QKV projection via MFMA. grid (BN,3,4), block 256 ----------------
__global__ __launch_bounds__(256)
void qkv_kernel(const float* __restrict__ padded, const float* __restrict__ tok,
                const float* __restrict__ Wq, const float* __restrict__ bq,
                const float* __restrict__ Wk, const float* __restrict__ bk,
                const float* __restrict__ Wv, const float* __restrict__ bv,
                const float* __restrict__ Wb1, const float* __restrict__ bb1,
                const float* __restrict__ Wb2,
                const float* __restrict__ Wv1, const float* __restrict__ bv1,
                const float* __restrict__ Wv2,
                float* __restrict__ Qo, float* __restrict__ Ko, float* __restrict__ Vo,
                float* __restrict__ CW, float* __restrict__ RVW,
                unsigned short* __restrict__ WV2F) {
    const int s = blockIdx.x;
    const int mat = blockIdx.y;
    const int chunk = blockIdx.z;
    const float* W = (mat == 0) ? Wq : (mat == 1) ? Wk : Wv;
    const float* bias = (mat == 0) ? bq : (mat == 1) ? bk : bv;
    float* outp = (mat == 0) ? Qo : (mat == 1) ? Ko : Vo;

    __shared__ unsigned short Xs[32][136];
    const int tid = threadIdx.x;

    {
        const int row = tid >> 3;
        const int colbase = (tid & 7) * 16;
        const int i = chunk * 32 + row;
        const float* src = (i == 0) ? tok : &padded[(size_t)s * TT * D + (size_t)(i - 1) * D];
#pragma unroll
        for (int k4 = 0; k4 < 4; ++k4) {
            float4 v = *(const float4*)&src[colbase + k4 * 4];
            unsigned lo = (unsigned)f2bf(v.x) | ((unsigned)f2bf(v.y) << 16);
            unsigned hi = (unsigned)f2bf(v.z) | ((unsigned)f2bf(v.w) << 16);
            *(uint2*)&Xs[row][colbase + k4 * 4] = make_uint2(lo, hi);
        }
    }
    __syncthreads();

    const int wave = tid >> 6;
    const int lane = tid & 63;
    const int hA = lane & 15;
    const int kg = lane >> 4;

    s16x8 afr[2][4];
#pragma unroll
    for (int m = 0; m < 2; ++m)
#pragma unroll
        for (int kt = 0; kt < 4; ++kt)
            afr[m][kt] = *(const s16x8*)&Xs[m * 16 + hA][kt * 32 + kg * 8];

    f32x4 acc[2][2];
#pragma unroll
    for (int m = 0; m < 2; ++m)
#pragma unroll
        for (int n = 0; n < 2; ++n) acc[m][n] = (f32x4){0.f, 0.f, 0.f, 0.f};

#pragma unroll
    for (int kt = 0; kt < 4; ++kt) {
#pragma unroll
        for (int n = 0; n < 2; ++n) {
            const int col = (2 * wave + n) * 16 + hA;
            s16x8 bw;
#pragma unroll
            for (int e = 0; e < 8; ++e)
                bw[e] = (short)f2bf(W[(size_t)(kt * 32 + kg * 8 + e) * D + col]);
            acc[0][n] = __builtin_amdgcn_mfma_f32_16x16x32_bf16(afr[0][kt], bw, acc[0][n], 0, 0, 0);
            acc[1][n] = __builtin_amdgcn_mfma_f32_16x16x32_bf16(afr[1][kt], bw, acc[1][n], 0, 0, 0);
        }
    }

#pragma unroll
    for (int n = 0; n < 2; ++n) {
        const int col = (2 * wave + n) * 16 + hA;
        const float bc = bias[col];
#pragma unroll
        for (int m = 0; m < 2; ++m)
#pragma unroll
            for (int r = 0; r < 4; ++r) {
                const int row = chunk * 32 + m * 16 + kg * 4 + r;
                outp[(size_t)s * L * D + (size_t)row * D + col] = acc[m][n][r] + bc;
            }
    }

    // ---- weight prepack (one block only; stream-serialized before K_mid/K3) ----
    if (s == 0 && mat == 0 && chunk == 0) {
        if (tid < 64) {
            const int u = tid;
            CW[u * 16 + 0] = Wb1[0 * 64 + u];
            CW[u * 16 + 1] = Wb1[1 * 64 + u];
            CW[u * 16 + 2] = Wb1[2 * 64 + u];
            CW[u * 16 + 3] = Wb1[3 * 64 + u] + Wb1[4 * 64 + u];
            CW[u * 16 + 4] = Wb1[5 * 64 + u];
            CW[u * 16 + 5] = bb1[u];
            CW[u * 16 + 6] = 0.f;
            CW[u * 16 + 7] = 0.f;
#pragma unroll
            for (int k = 0; k < 8; ++k) CW[u * 16 + 8 + k] = Wb2[u * 8 + k];
        }
        if (tid < 128) {
            const int cc = tid;
            RVW[cc * 8 + 0] = Wv1[0 * 128 + cc];
            RVW[cc * 8 + 1] = Wv1[1 * 128 + cc];
            RVW[cc * 8 + 2] = Wv1[2 * 128 + cc];
            RVW[cc * 8 + 3] = Wv1[3 * 128 + cc] + Wv1[4 * 128 + cc];
            RVW[cc * 8 + 4] = Wv1[5 * 128 + cc];
            RVW[cc * 8 + 5] = bv1[cc];
            RVW[cc * 8 + 6] = 0.f;
            RVW[cc * 8 + 7] = 0.f;
        }
        for (int idx = tid; idx < 16384; idx += 256) {
            int f = idx >> 9, r = idx & 511, ln = r >> 3, e = r & 7;
            int kt = f >> 3, ng = f & 7;
            int row = kt * 32 + (ln >> 4) * 8 + e;
            int col = ng * 16 + (ln & 15);
            WV2F[idx] = f2bf(Wv2[(size_t)row * D + col]);
        }
    }
}

// ---------------- K_mid: merged logits (blocks <256) + bias MLP (blocks >=256) ----------------
// Logits: per (s,h) MFMA -> LW (raw logits, no bias).
// Bias: wave <-> (j, i-half), lanes <-> i; masked-j waves exit immediately
// (~49% of waves). Output BIAS[s][j][i][8] bf16, coalesced 16B stores.
__global__ __launch_bounds__(256)
void mid_kernel(const float* __restrict__ Q, const float* __restrict__ K,
                const int* __restrict__ masks,
                const float* __restrict__ pos3d, const float* __restrict__ CW,
                const float* __restrict__ bb2,
                __hip_bfloat16* __restrict__ LW, unsigned short* __restrict__ BIAS) {
    const int bid = blockIdx.x;
    const int tid = threadIdx.x;

    __shared__ float Qs[128][16];
    __shared__ float Ks[128][16];

    if (bid < 256) {
        // ---------- logits via MFMA ----------
        const int s = bid >> 3;
        const int h = bid & 7;
        const int wv = tid >> 6;
        const int lane = tid & 63;
        const int lrn = lane & 15;
        const int kg = lane >> 4;

        for (int e = tid; e < 2048; e += 256) {
            int i = e >> 4, d = e & 15;
            Qs[i][d] = Q[((size_t)s * L + i) * D + h * 16 + d];
            Ks[i][d] = K[((size_t)s * L + i) * D + h * 16 + d];
        }
        __syncthreads();

        s16x8 afr[2];
#pragma unroll
        for (int m = 0; m < 2; ++m) {
            s16x8 a;
#pragma unroll
            for (int e = 0; e < 8; ++e) a[e] = 0;
            if (kg < 2) {
                const int i = wv * 32 + m * 16 + lrn;
                float4 q0 = *(const float4*)&Qs[i][kg * 8];
                float4 q1 = *(const float4*)&Qs[i][kg * 8 + 4];
                a[0] = (short)f2bf(q0.x); a[1] = (short)f2bf(q0.y);
                a[2] = (short)f2bf(q0.z); a[3] = (short)f2bf(q0.w);
                a[4] = (short)f2bf(q1.x); a[5] = (short)f2bf(q1.y);
                a[6] = (short)f2bf(q1.z); a[7] = (short)f2bf(q1.w);
            }
            afr[m] = a;
        }

        __hip_bfloat16* lw = LW + ((size_t)(s * NH + h) * L) * L;
#pragma unroll
        for (int n = 0; n < 8; ++n) {
            s16x8 b;
#pragma unroll
            for (int e = 0; e < 8; ++e) b[e] = 0;
            if (kg < 2) {
                const int j = n * 16 + lrn;
                float4 k0 = *(const float4*)&Ks[j][kg * 8];
                float4 k1 = *(const float4*)&Ks[j][kg * 8 + 4];
                b[0] = (short)f2bf(k0.x); b[1] = (short)f2bf(k0.y);
                b[2] = (short)f2bf(k0.z); b[3] = (short)f2bf(k0.w);
                b[4] = (short)f2bf(k1.x); b[5] = (short)f2bf(k1.y);
                b[6] = (short)f2bf(k1.z); b[7] = (short)f2bf(k1.w);
            }
#pragma unroll
            for (int m = 0; m < 2; ++m) {
                f32x4 acc = (f32x4){0.f, 0.f, 0.f, 0.f};
                acc = __builtin_amdgcn_mfma_f32_16x16x32_bf16(afr[m], b, acc, 0, 0, 0);
#pragma unroll
                for (int r = 0; r < 4; ++r)
                    lw[(size_t)(wv * 32 + m * 16 + kg * 4 + r) * L + n * 16 + lrn] =
                        __float2bfloat16(acc[r] * 0.25f);
            }
        }
    } else {
        // ---------- bias MLP ----------
        const int b2 = bid - 256;
        const int s = b2 >> 6;
        const int jp = b2 & 63;
        const int wv = tid >> 6;
        const int lane = tid & 63;
        const int j = jp * 2 + (wv >> 1);
        const int i = (wv & 1) * 64 + lane;

        if (j == 0) return;                                   // col 0 zeroed
        if (!masks[(size_t)s * TT + (j - 1)]) return;         // masked j: w==0, bias unused
        if (i == 0) return;                                   // row 0 zeroed

        const float* pi = pos3d + ((size_t)s * TT + (i - 1)) * 3;
        const float* pj = pos3d + ((size_t)s * TT + (j - 1)) * 3;
        const float dx = pi[0] - pj[0], dy = pi[1] - pj[1], dz = pi[2] - pj[2];
        const float dist2 = dx * dx + dy * dy + dz * dz;
        const float dist = sqrtf(dist2);

        float bias[NH];
#pragma unroll
        for (int hh = 0; hh < NH; ++hh) bias[hh] = 0.f;
        const float4* cw4 = (const float4*)CW;
#pragma unroll 2
        for (int u = 0; u < 64; ++u) {
            float4 wa  = cw4[u * 4 + 0];
            float4 wb  = cw4[u * 4 + 1];
            float4 w2a = cw4[u * 4 + 2];
            float4 w2b = cw4[u * 4 + 3];
            float hv = wb.y;
            hv = fmaf(dx, wa.x, hv);
            hv = fmaf(dy, wa.y, hv);
            hv = fmaf(dz, wa.z, hv);
            hv = fmaf(dist, wa.w, hv);
            hv = fmaf(dist2, wb.x, hv);
            hv = gelu_sig(hv);
            bias[0] = fmaf(hv, w2a.x, bias[0]);
            bias[1] = fmaf(hv, w2a.y, bias[1]);
            bias[2] = fmaf(hv, w2a.z, bias[2]);
            bias[3] = fmaf(hv, w2a.w, bias[3]);
            bias[4] = fmaf(hv, w2b.x, bias[4]);
            bias[5] = fmaf(hv, w2b.y, bias[5]);
            bias[6] = fmaf(hv, w2b.z, bias[6]);
            bias[7] = fmaf(hv, w2b.w, bias[7]);
        }
        uint4 ow;
        ow.x = (unsigned)f2bf(bias[0] + bb2[0]) | ((unsigned)f2bf(bias[1] + bb2[1]) << 16);
        ow.y = (unsigned)f2bf(bias[2] + bb2[2]) | ((unsigned)f2bf(bias[3] + bb2[3]) << 16);
        ow.z = (unsigned)f2bf(bias[4] + bb2[4]) | ((unsigned)f2bf(bias[5] + bb2[5]) << 16);
        ow.w = (unsigned)f2bf(bias[6] + bb2[6]) | ((unsigned)f2bf(bias[7] + bb2[7]) << 16);
        *(uint4*)&BIAS[(((size_t)s * L + j) * L + i) * 8] = ow;
    }
}

// ---------------- K3: core per (s,i). grid (L, BN), block 256 (4 waves) ----------------
__global__ __launch_bounds__(256, 4)
void attn_kernel(const float* __restrict__ padded, const int* __restrict__ masks,
                 const float* __restrict__ pos3d,
                 const float* __restrict__ gamma, const float* __restrict__ beta,
                 const float* __restrict__ tok,
                 const float* __restrict__ RVW,
                 const unsigned short* __restrict__ WV2F,
                 const float* __restrict__ bv2,
                 const float* __restrict__ V, const __hip_bfloat16* __restrict__ LW,
                 const unsigned short* __restrict__ BIAS,
                 float* __restrict__ out) {
    const int i = blockIdx.x;
    const int s = blockIdx.y;
    const int tid = threadIdx.x;
    const int wave = tid >> 6;
    const int lane = tid & 63;
    const int hA = lane & 15;
    const int kg = lane >> 4;
    const int j = tid & 127;
    const int hbase = (tid >> 7) * 4;

    __shared__ float4 feat4_lds[144];
    __shared__ float  feat5_lds[L];
    __shared__ unsigned short w_bf[NH][136];
    __shared__ unsigned short gs_bf[NH][136];
    __shared__ float  a1_part[8][132];
    __shared__ float  a2_lds[D];
    __shared__ float  reds[4][NH];
    __shared__ float  red2[2][2];
    __shared__ unsigned long long kb_lds[2];
    __shared__ int    jmap_lds[128];

    // ---- early loads: 4 heads' logits + bias + mask ----
    __hip_bfloat16 lr4[4];
#pragma unroll
    for (int k = 0; k < 4; ++k)
        lr4[k] = LW[((size_t)(s * NH + hbase + k) * L + i) * L + j];
    const int keep = (j == 0) ? 1 : masks[(size_t)s * TT + (j - 1)];
    const int ub = (i > 0) && (j > 0) && keep;
    uint2 braw = make_uint2(0u, 0u);
    if (ub) braw = *(const uint2*)&BIAS[(((size_t)s * L + j) * L + i) * 8 + hbase];

    const unsigned long long bal = __ballot(keep != 0);
    if (lane == 0 && wave < 2) kb_lds[wave] = bal;

    // ---- relative features (threads 0-127) ----
    if (tid < 128) {
        float pix = 0.f, piy = 0.f, piz = 0.f;
        if (i > 0) { const float* pp = pos3d + ((size_t)s * TT + (i - 1)) * 3; pix = pp[0]; piy = pp[1]; piz = pp[2]; }
        float pjx = 0.f, pjy = 0.f, pjz = 0.f;
        if (tid > 0) { const float* pp = pos3d + ((size_t)s * TT + (tid - 1)) * 3; pjx = pp[0]; pjy = pp[1]; pjz = pp[2]; }
        const float dx = pix - pjx, dy = piy - pjy, dz = piz - pjz;
        const float dist2 = dx * dx + dy * dy + dz * dz;
        const float dist = sqrtf(dist2);
        feat4_lds[tid + (tid >> 3)] = make_float4(dx, dy, dz, dist);
        feat5_lds[tid] = dist2;
        jmap_lds[tid] = 0;
    }
    for (int idx = tid; idx < NH * 68; idx += 256) ((unsigned*)w_bf)[idx] = 0u;
    __syncthreads();                       // A

    const unsigned long long b0 = kb_lds[0];
    const int nk = __popcll(b0) + __popcll(kb_lds[1]);
    const int NK32 = (nk + 31) >> 5;
    int rank = 0;
    if (keep) {
        rank = __popcll(bal & ((1ull << lane) - 1)) + ((wave & 1) ? __popcll(b0) : 0);
        if (wave < 2) jmap_lds[rank] = j;
    }

    // ---- softmax: 4 heads per thread-half ----
    float badd[4];
    badd[0] = bf2f((unsigned short)(braw.x & 0xffffu));
    badd[1] = bf2f((unsigned short)(braw.x >> 16));
    badd[2] = bf2f((unsigned short)(braw.y & 0xffffu));
    badd[3] = bf2f((unsigned short)(braw.y >> 16));
    float p4[4];
#pragma unroll
    for (int k = 0; k < 4; ++k) {
        float lv = __bfloat162float(lr4[k]) + badd[k];
        p4[k] = keep ? __expf(lv) : 0.f;
    }
#pragma unroll
    for (int k = 0; k < 4; ++k) {
        float v = p4[k];
        for (int off = 32; off >= 1; off >>= 1) v += __shfl_xor(v, off, 64);
        if (lane == 0) reds[wave][hbase + k] = v;
    }
    __syncthreads();                       // B
    if (keep) {
        const int pb = (tid >> 7) * 2;
#pragma unroll
        for (int k = 0; k < 4; ++k) {
            const int hh = hbase + k;
            float inv = __builtin_amdgcn_rcpf(reds[pb][hh] + reds[pb + 1][hh]);
            w_bf[hh][rank] = f2bf(p4[k] * inv);
        }
    }
    __syncthreads();                       // C

    // ---- pass 2 ----
    const int jg = tid >> 5;
    const int c0v = (tid & 31) * 4;
    const int h0v = c0v >> 4;
    const int perg = NK32 * 4;
    const float* Vs = V + (size_t)s * L * D;

    if (i > 0) {
        const int ng0 = 2 * wave;
        float rvw[2][6];
#pragma unroll
        for (int n = 0; n < 2; ++n) {
            const int c = (ng0 + n) * 16 + hA;
            float4 ra = *(const float4*)&RVW[(size_t)c * 8 + 0];
            rvw[n][0] = ra.x; rvw[n][1] = ra.y; rvw[n][2] = ra.z; rvw[n][3] = ra.w;
            rvw[n][4] = RVW[(size_t)c * 8 + 4];
            rvw[n][5] = RVW[(size_t)c * 8 + 5];
        }

        f32x4 accG[2];
#pragma unroll
        for (int n = 0; n < 2; ++n) accG[n] = (f32x4){0.f, 0.f, 0.f, 0.f};

#pragma unroll
        for (int kt = 0; kt < 4; ++kt) {
            if (kt >= NK32) break;
            s16x8 wf;
#pragma unroll
            for (int e = 0; e < 8; ++e) wf[e] = 0;
            if (hA < NH) {
                wf = *(const s16x8*)&w_bf[hA][kt * 32 + kg * 8];
                if (kt == 0 && kg == 0) wf[0] = 0;
            }
            s16x8 bfr[2];
#pragma unroll
            for (int e = 0; e < 8; ++e) {
                const int jj = jmap_lds[kt * 32 + kg * 8 + e];
                float4 fa = feat4_lds[jj + (jj >> 3)];
                float f5 = feat5_lds[jj];
#pragma unroll
                for (int n = 0; n < 2; ++n) {
                    float hv = rvw[n][5];
                    hv = fmaf(fa.x, rvw[n][0], hv);
                    hv = fmaf(fa.y, rvw[n][1], hv);
                    hv = fmaf(fa.z, rvw[n][2], hv);
                    hv = fmaf(fa.w, rvw[n][3], hv);
                    hv = fmaf(f5,  rvw[n][4], hv);
                    bfr[n][e] = (short)f2bf(gelu_sig(hv));
                }
            }
#pragma unroll
            for (int n = 0; n < 2; ++n)
                accG[n] = __builtin_amdgcn_mfma_f32_16x16x32_bf16(wf, bfr[n], accG[n], 0, 0, 0);
        }

        // ---- a1 over compacted keys (8 groups) ----
        float a1a[4] = {0.f, 0.f, 0.f, 0.f};
        for (int r = 0; r < perg; ++r) {
            const int jt = jg * perg + r;
            const int jr = jmap_lds[jt];
            float4 vcur = *(const float4*)&Vs[(size_t)jr * D + c0v];
            const float wj = bf2f(w_bf[h0v][jt]);
            a1a[0] = fmaf(wj, vcur.x, a1a[0]);
            a1a[1] = fmaf(wj, vcur.y, a1a[1]);
            a1a[2] = fmaf(wj, vcur.z, a1a[2]);
            a1a[3] = fmaf(wj, vcur.w, a1a[3]);
        }
        *(float4*)&a1_part[jg][c0v] = make_float4(a1a[0], a1a[1], a1a[2], a1a[3]);

        if (lane < 32) {
#pragma unroll
            for (int n = 0; n < 2; ++n)
#pragma unroll
                for (int r = 0; r < 4; ++r)
                    gs_bf[(lane >> 4) * 4 + r][(ng0 + n) * 16 + hA] = f2bf(accG[n][r]);
        }
        __syncthreads();

        // ---- a2 = GS @ Wv2 via MFMA (2 col-frags per wave) ----
        f32x4 acc2[2];
#pragma unroll
        for (int n = 0; n < 2; ++n) acc2[n] = (f32x4){0.f, 0.f, 0.f, 0.f};
#pragma unroll
        for (int kt = 0; kt < 4; ++kt) {
            s16x8 gf;
#pragma unroll
            for (int e = 0; e < 8; ++e) gf[e] = 0;
            if (hA < NH)
                gf = *(const s16x8*)&gs_bf[hA][kt * 32 + kg * 8];
#pragma unroll
            for (int n = 0; n < 2; ++n) {
                const int f = kt * 8 + ng0 + n;
                s16x8 bw = *(const s16x8*)&WV2F[((size_t)f * 64 + lane) * 8];
                acc2[n] = __builtin_amdgcn_mfma_f32_16x16x32_bf16(gf, bw, acc2[n], 0, 0, 0);
            }
        }
#pragma unroll
        for (int n = 0; n < 2; ++n) {
            const int f = ng0 + n;
            if (kg == (f >> 2)) a2_lds[f * 16 + hA] = acc2[n][f & 3];
        }
        __syncthreads();

        if (tid < 128) {
            float a1f = a1_part[0][tid] + a1_part[1][tid] + a1_part[2][tid] + a1_part[3][tid]
                      + a1_part[4][tid] + a1_part[5][tid] + a1_part[6][tid] + a1_part[7][tid];
            const float S1 = 1.0f - bf2f(w_bf[tid >> 4][0]);
            const size_t o = (size_t)s * TT * D + (size_t)(i - 1) * D + tid;
            out[o] = a1f + a2_lds[tid] + S1 * bv2[tid] + padded[o];
        }
    } else {
        // ---- cls row: a2 == 0; V-reduce + layernorm ----
        float a1a[4] = {0.f, 0.f, 0.f, 0.f};
        for (int r = 0; r < perg; ++r) {
            const int jt = jg * perg + r;
            const int jr = jmap_lds[jt];
            float4 vcur = *(const float4*)&Vs[(size_t)jr * D + c0v];
            const float wj = bf2f(w_bf[h0v][jt]);
            a1a[0] = fmaf(wj, vcur.x, a1a[0]);
            a1a[1] = fmaf(wj, vcur.y, a1a[1]);
            a1a[2] = fmaf(wj, vcur.z, a1a[2]);
            a1a[3] = fmaf(wj, vcur.w, a1a[3]);
        }
        *(float4*)&a1_part[jg][c0v] = make_float4(a1a[0], a1a[1], a1a[2], a1a[3]);
        __syncthreads();

        float st = 0.f;
        if (tid < 128) {
            float a1f = a1_part[0][tid] + a1_part[1][tid] + a1_part[2][tid] + a1_part[3][tid]
                      + a1_part[4][tid] + a1_part[5][tid] + a1_part[6][tid] + a1_part[7][tid];
            st = a1f + tok[tid];
            float sum = st, sum2 = st * st;
            for (int off = 32; off >= 1; off >>= 1) {
                sum += __shfl_xor(sum, off, 64);
                sum2 += __shfl_xor(sum2, off, 64);
            }
            if (lane == 0) { red2[wave][0] = sum; red2[wave][1] = sum2; }
        }
        __syncthreads();
        if (tid < 128) {
            float sum = red2[0][0] + red2[1][0];
            float sum2 = red2[0][1] + red2[1][1];
            const float mu = sum * (1.0f / 128.0f);
            const float var = sum2 * (1.0f / 128.0f) - mu * mu;
            const float y = (st - mu) * rsqrtf(var + 1e-5f) * gamma[tid] + beta[tid];
            out[(size_t)BN * TT * D + (size_t)s * D + tid] = y;
        }
    }
}

extern "C" void kernel_launch(void* const* d_in, const int* in_sizes, int n_in,
                              void* d_out, int out_size, void* d_ws, size_t ws_size,
                              hipStream_t stream) {
    const float* padded = (const float*)d_in[0];
    const int*   masks  = (const int*)d_in[1];
    const float* pos3d  = (const float*)d_in[2];
    const float* Wq = (const float*)d_in[3];
    const float* bq = (const float*)d_in[4];
    const float* Wk = (const float*)d_in[5];
    const float* bk = (const float*)d_in[6];
    const float* Wv = (const float*)d_in[7];
    const float* bv = (const float*)d_in[8];
    const float* gamma = (const float*)d_in[9];
    const float* beta  = (const float*)d_in[10];
    const float* tok   = (const float*)d_in[11];
    const float* Wb1 = (const float*)d_in[12];
    const float* bb1 = (const float*)d_in[13];
    const float* Wb2 = (const float*)d_in[14];
    const float* bb2 = (const float*)d_in[15];
    const float* Wv1 = (const float*)d_in[16];
    const float* bv1 = (const float*)d_in[17];
    const float* Wv2 = (const float*)d_in[18];
    const float* bv2 = (const float*)d_in[19];
    float* out = (float*)d_out;

    float* Q  = (float*)d_ws;
    float* K  = Q + (size_t)BN * L * D;
    float* Vw = K + (size_t)BN * L * D;
    __hip_bfloat16* LW = (__hip_bfloat16*)(Vw + (size_t)BN * L * D);
    unsigned short* BIAS = (unsigned short*)(LW + (size_t)BN * NH * L * L);
    float* CW  = (float*)(BIAS + (size_t)BN * L * L * NH);
    float* RVW = CW + 64 * 16;
    unsigned short* WV2F = (unsigned short*)(RVW + 128 * 8);

    qkv_kernel<<<dim3(BN, 3, 4), 256, 0, stream>>>(padded, tok, Wq, bq, Wk, bk, Wv, bv,
                                                   Wb1, bb1, Wb2, Wv1, bv1, Wv2,
                                                   Q, K, Vw, CW, RVW, WV2F);
    mid_kernel<<<dim3(256 + BN * 64), 256, 0, stream>>>(Q, K, masks, pos3d, CW, bb2, LW, BIAS);
    attn_kernel<<<dim3(L, BN), 256, 0, stream>>>(padded, masks, pos3d, gamma, beta, tok,
                                                 RVW, WV2F, bv2,
                                                 Vw, LW, BIAS, out);
}

// Round 11
// 74.452 us; speedup vs baseline: 1.2135x; 1.0624x over previous
//
#include <hip/hip_runtime.h>
#include <hip/hip_bf16.h>
#include <math.h>

#define BN 32
#define L 128
#define D 128
#define TT 127
#define NH 8

typedef float f32x4 __attribute__((ext_vector_type(4)));
typedef short s16x8 __attribute__((ext_vector_type(8)));

__device__ __forceinline__ float gelu_sig(float x) {
    float e = __expf(-1.702f * x);
    return x * __builtin_amdgcn_rcpf(1.0f + e);
}
__device__ __forceinline__ unsigned short f2bf(float f) {
    unsigned u = __float_as_uint(f);
    return (unsigned short)((u + 0x7fffu + ((u >> 16) & 1u)) >> 16);
}
__device__ __forceinline__ float bf2f(unsigned short v) {
    return __uint_as_float((unsigned)v << 16);
}

// ---------------- K1: qkv (blocks 0..383) + bias MLP (blocks 384..2431) ----------------
// qkv: MFMA projection, one (s, mat, 32-row chunk) per block.
// bias: wave <-> (j, i-half), lanes <-> i; masked-j waves exit at instr ~10.
//       Writes BIAS[s][i][j][8] bf16 (i-major -> K3 reads coalesced).
__global__ __launch_bounds__(256)
void qkv_bias_kernel(const float* __restrict__ padded, const float* __restrict__ tok,
                     const float* __restrict__ Wq, const float* __restrict__ bq,
                     const float* __restrict__ Wk, const float* __restrict__ bk,
                     const float* __restrict__ Wv, const float* __restrict__ bv,
                     const float* __restrict__ Wb1, const float* __restrict__ bb1,
                     const float* __restrict__ Wb2, const float* __restrict__ bb2,
                     const float* __restrict__ Wv1, const float* __restrict__ bv1,
                     const float* __restrict__ Wv2,
                     const int* __restrict__ masks, const float* __restrict__ pos3d,
                     float* __restrict__ Qo, float* __restrict__ Ko, float* __restrict__ Vo,
                     float* __restrict__ RVW, unsigned short* __restrict__ WV2F,
                     unsigned short* __restrict__ BIAS) {
    const int bid = blockIdx.x;
    const int tid = threadIdx.x;

    if (bid < 384) {
        // ---------------- qkv ----------------
        const int chunk = bid / 96;
        const int rem = bid % 96;
        const int mat = rem >> 5;
        const int s = rem & 31;
        const float* W = (mat == 0) ? Wq : (mat == 1) ? Wk : Wv;
        const float* bias = (mat == 0) ? bq : (mat == 1) ? bk : bv;
        float* outp = (mat == 0) ? Qo : (mat == 1) ? Ko : Vo;

        __shared__ unsigned short Xs[32][136];
        {
            const int row = tid >> 3;
            const int colbase = (tid & 7) * 16;
            const int i = chunk * 32 + row;
            const float* src = (i == 0) ? tok : &padded[(size_t)s * TT * D + (size_t)(i - 1) * D];
#pragma unroll
            for (int k4 = 0; k4 < 4; ++k4) {
                float4 v = *(const float4*)&src[colbase + k4 * 4];
                unsigned lo = (unsigned)f2bf(v.x) | ((unsigned)f2bf(v.y) << 16);
                unsigned hi = (unsigned)f2bf(v.z) | ((unsigned)f2bf(v.w) << 16);
                *(uint2*)&Xs[row][colbase + k4 * 4] = make_uint2(lo, hi);
            }
        }
        __syncthreads();

        const int wave = tid >> 6;
        const int lane = tid & 63;
        const int hA = lane & 15;
        const int kg = lane >> 4;

        s16x8 afr[2][4];
#pragma unroll
        for (int m = 0; m < 2; ++m)
#pragma unroll
            for (int kt = 0; kt < 4; ++kt)
                afr[m][kt] = *(const s16x8*)&Xs[m * 16 + hA][kt * 32 + kg * 8];

        f32x4 acc[2][2];
#pragma unroll
        for (int m = 0; m < 2; ++m)
#pragma unroll
            for (int n = 0; n < 2; ++n) acc[m][n] = (f32x4){0.f, 0.f, 0.f, 0.f};

#pragma unroll
        for (int kt = 0; kt < 4; ++kt) {
#pragma unroll
            for (int n = 0; n < 2; ++n) {
                const int col = (2 * wave + n) * 16 + hA;
                s16x8 bw;
#pragma unroll
                for (int e = 0; e < 8; ++e)
                    bw[e] = (short)f2bf(W[(size_t)(kt * 32 + kg * 8 + e) * D + col]);
                acc[0][n] = __builtin_amdgcn_mfma_f32_16x16x32_bf16(afr[0][kt], bw, acc[0][n], 0, 0, 0);
                acc[1][n] = __builtin_amdgcn_mfma_f32_16x16x32_bf16(afr[1][kt], bw, acc[1][n], 0, 0, 0);
            }
        }

#pragma unroll
        for (int n = 0; n < 2; ++n) {
            const int col = (2 * wave + n) * 16 + hA;
            const float bc = bias[col];
#pragma unroll
            for (int m = 0; m < 2; ++m)
#pragma unroll
                for (int r = 0; r < 4; ++r) {
                    const int row = chunk * 32 + m * 16 + kg * 4 + r;
                    outp[(size_t)s * L * D + (size_t)row * D + col] = acc[m][n][r] + bc;
                }
        }

        // ---- RVW / WV2F prepack (block 0 only; consumed 2 launches later) ----
        if (bid == 0) {
            if (tid < 128) {
                const int cc = tid;
                RVW[cc * 8 + 0] = Wv1[0 * 128 + cc];
                RVW[cc * 8 + 1] = Wv1[1 * 128 + cc];
                RVW[cc * 8 + 2] = Wv1[2 * 128 + cc];
                RVW[cc * 8 + 3] = Wv1[3 * 128 + cc] + Wv1[4 * 128 + cc];
                RVW[cc * 8 + 4] = Wv1[5 * 128 + cc];
                RVW[cc * 8 + 5] = bv1[cc];
                RVW[cc * 8 + 6] = 0.f;
                RVW[cc * 8 + 7] = 0.f;
            }
            for (int idx = tid; idx < 16384; idx += 256) {
                int f = idx >> 9, r = idx & 511, ln = r >> 3, e = r & 7;
                int kt = f >> 3, ng = f & 7;
                int row = kt * 32 + (ln >> 4) * 8 + e;
                int col = ng * 16 + (ln & 15);
                WV2F[idx] = f2bf(Wv2[(size_t)row * D + col]);
            }
        }
    } else {
        // ---------------- bias MLP ----------------
        const int b2 = bid - 384;
        const int s = b2 >> 6;
        const int jp = b2 & 63;
        const int wv = tid >> 6;
        const int lane = tid & 63;
        const int j = jp * 2 + (wv >> 1);
        const int i = (wv & 1) * 64 + lane;

        if (j == 0) return;                                   // col 0 zeroed
        if (!masks[(size_t)s * TT + (j - 1)]) return;         // masked j: w==0
        // i==0 lanes compute with pix=0 (store suppressed below)
        const float* pj = pos3d + ((size_t)s * TT + (j - 1)) * 3;
        const int im1 = (i > 0) ? (i - 1) : 0;
        const float* pi = pos3d + ((size_t)s * TT + im1) * 3;
        const float pix = (i > 0) ? pi[0] : 0.f;
        const float piy = (i > 0) ? pi[1] : 0.f;
        const float piz = (i > 0) ? pi[2] : 0.f;
        const float dx = pix - pj[0], dy = piy - pj[1], dz = piz - pj[2];
        const float dist2 = dx * dx + dy * dy + dz * dz;
        const float dist = sqrtf(dist2);

        float bias[NH];
#pragma unroll
        for (int hh = 0; hh < NH; ++hh) bias[hh] = 0.f;
#pragma unroll 2
        for (int u = 0; u < 64; ++u) {
            // wave-uniform -> scalar loads
            const float w0 = Wb1[u];
            const float w1 = Wb1[64 + u];
            const float w2 = Wb1[128 + u];
            const float w3 = Wb1[192 + u] + Wb1[256 + u];
            const float w4 = Wb1[320 + u];
            float hv = bb1[u];
            hv = fmaf(dx, w0, hv);
            hv = fmaf(dy, w1, hv);
            hv = fmaf(dz, w2, hv);
            hv = fmaf(dist, w3, hv);
            hv = fmaf(dist2, w4, hv);
            hv = gelu_sig(hv);
            const float* w2p = &Wb2[u * 8];
            bias[0] = fmaf(hv, w2p[0], bias[0]);
            bias[1] = fmaf(hv, w2p[1], bias[1]);
            bias[2] = fmaf(hv, w2p[2], bias[2]);
            bias[3] = fmaf(hv, w2p[3], bias[3]);
            bias[4] = fmaf(hv, w2p[4], bias[4]);
            bias[5] = fmaf(hv, w2p[5], bias[5]);
            bias[6] = fmaf(hv, w2p[6], bias[6]);
            bias[7] = fmaf(hv, w2p[7], bias[7]);
        }
        if (i > 0) {
            uint4 ow;
            ow.x = (unsigned)f2bf(bias[0] + bb2[0]) | ((unsigned)f2bf(bias[1] + bb2[1]) << 16);
            ow.y = (unsigned)f2bf(bias[2] + bb2[2]) | ((unsigned)f2bf(bias[3] + bb2[3]) << 16);
            ow.z = (unsigned)f2bf(bias[4] + bb2[4]) | ((unsigned)f2bf(bias[5] + bb2[5]) << 16);
            ow.w = (unsigned)f2bf(bias[6] + bb2[6]) | ((unsigned)f2bf(bias[7] + bb2[7]) << 16);
            *(uint4*)&BIAS[(((size_t)s * L + i) * L + j) * 8] = ow;   // i-major
        }
    }
}

// ---------------- K2: logits via MFMA. grid (BN*NH), block 256 ----------------
__global__ __launch_bounds__(256)
void logits_kernel(const float* __restrict__ Q, const float* __restrict__ K,
                   __hip_bfloat16* __restrict__ LW) {
    const int s = blockIdx.x >> 3;
    const int h = blockIdx.x & 7;
    const int tid = threadIdx.x;
    const int wv = tid >> 6;
    const int lane = tid & 63;
    const int lrn = lane & 15;
    const int kg = lane >> 4;

    __shared__ float Qs[128][16];
    __shared__ float Ks[128][16];
    for (int e = tid; e < 2048; e += 256) {
        int i = e >> 4, d = e & 15;
        Qs[i][d] = Q[((size_t)s * L + i) * D + h * 16 + d];
        Ks[i][d] = K[((size_t)s * L + i) * D + h * 16 + d];
    }
    __syncthreads();

    s16x8 afr[2];
#pragma unroll
    for (int m = 0; m < 2; ++m) {
        s16x8 a;
#pragma unroll
        for (int e = 0; e < 8; ++e) a[e] = 0;
        if (kg < 2) {
            const int i = wv * 32 + m * 16 + lrn;
            float4 q0 = *(const float4*)&Qs[i][kg * 8];
            float4 q1 = *(const float4*)&Qs[i][kg * 8 + 4];
            a[0] = (short)f2bf(q0.x); a[1] = (short)f2bf(q0.y);
            a[2] = (short)f2bf(q0.z); a[3] = (short)f2bf(q0.w);
            a[4] = (short)f2bf(q1.x); a[5] = (short)f2bf(q1.y);
            a[6] = (short)f2bf(q1.z); a[7] = (short)f2bf(q1.w);
        }
        afr[m] = a;
    }

    __hip_bfloat16* lw = LW + ((size_t)(s * NH + h) * L) * L;
#pragma unroll
    for (int n = 0; n < 8; ++n) {
        s16x8 b;
#pragma unroll
        for (int e = 0; e < 8; ++e) b[e] = 0;
        if (kg < 2) {
            const int j = n * 16 + lrn;
            float4 k0 = *(const float4*)&Ks[j][kg * 8];
            float4 k1 = *(const float4*)&Ks[j][kg * 8 + 4];
            b[0] = (short)f2bf(k0.x); b[1] = (short)f2bf(k0.y);
            b[2] = (short)f2bf(k0.z); b[3] = (short)f2bf(k0.w);
            b[4] = (short)f2bf(k1.x); b[5] = (short)f2bf(k1.y);
            b[6] = (short)f2bf(k1.z); b[7] = (short)f2bf(k1.w);
        }
#pragma unroll
        for (int m = 0; m < 2; ++m) {
            f32x4 acc = (f32x4){0.f, 0.f, 0.f, 0.f};
            acc = __builtin_amdgcn_mfma_f32_16x16x32_bf16(afr[m], b, acc, 0, 0, 0);
#pragma unroll
            for (int r = 0; r < 4; ++r)
                lw[(size_t)(wv * 32 + m * 16 + kg * 4 + r) * L + n * 16 + lrn] =
                    __float2bfloat16(acc[r] * 0.25f);
        }
    }
}

// ---------------- K3: core per (s,i). grid (L, BN), block 256 (4 waves) ----------------
__global__ __launch_bounds__(256, 4)
void attn_kernel(const float* __restrict__ padded, const int* __restrict__ masks,
                 const float* __restrict__ pos3d,
                 const float* __restrict__ gamma, const float* __restrict__ beta,
                 const float* __restrict__ tok,
                 const float* __restrict__ RVW,
                 const unsigned short* __restrict__ WV2F,
                 const float* __restrict__ bv2,
                 const float* __restrict__ V, const __hip_bfloat16* __restrict__ LW,
                 const unsigned short* __restrict__ BIAS,
                 float* __restrict__ out) {
    const int i = blockIdx.x;
    const int s = blockIdx.y;
    const int tid = threadIdx.x;
    const int wave = tid >> 6;
    const int lane = tid & 63;
    const int hA = lane & 15;
    const int kg = lane >> 4;
    const int j = tid & 127;
    const int hbase = (tid >> 7) * 4;

    __shared__ float4 feat4_lds[144];
    __shared__ float  feat5_lds[L];
    __shared__ unsigned short w_bf[NH][136];
    __shared__ unsigned short gs_bf[NH][136];
    __shared__ float  a1_part[8][132];
    __shared__ float  a2_lds[D];
    __shared__ float  reds[4][NH];
    __shared__ float  red2[2][2];
    __shared__ unsigned long long kb_lds[2];
    __shared__ int    jmap_lds[128];

    // ---- early loads: 4 heads' logits + bias (coalesced, i-major) + mask ----
    __hip_bfloat16 lr4[4];
#pragma unroll
    for (int k = 0; k < 4; ++k)
        lr4[k] = LW[((size_t)(s * NH + hbase + k) * L + i) * L + j];
    const int keep = (j == 0) ? 1 : masks[(size_t)s * TT + (j - 1)];
    const int ub = (i > 0) && (j > 0) && keep;
    uint2 braw = make_uint2(0u, 0u);
    if (ub) braw = *(const uint2*)&BIAS[(((size_t)s * L + i) * L + j) * 8 + hbase];

    const unsigned long long bal = __ballot(keep != 0);
    if (lane == 0 && wave < 2) kb_lds[wave] = bal;

    // ---- relative features (threads 0-127) ----
    if (tid < 128) {
        float pix = 0.f, piy = 0.f, piz = 0.f;
        if (i > 0) { const float* pp = pos3d + ((size_t)s * TT + (i - 1)) * 3; pix = pp[0]; piy = pp[1]; piz = pp[2]; }
        float pjx = 0.f, pjy = 0.f, pjz = 0.f;
        if (tid > 0) { const float* pp = pos3d + ((size_t)s * TT + (tid - 1)) * 3; pjx = pp[0]; pjy = pp[1]; pjz = pp[2]; }
        const float dx = pix - pjx, dy = piy - pjy, dz = piz - pjz;
        const float dist2 = dx * dx + dy * dy + dz * dz;
        const float dist = sqrtf(dist2);
        feat4_lds[tid + (tid >> 3)] = make_float4(dx, dy, dz, dist);
        feat5_lds[tid] = dist2;
        jmap_lds[tid] = 0;
    }
    for (int idx = tid; idx < NH * 68; idx += 256) ((unsigned*)w_bf)[idx] = 0u;
    __syncthreads();                       // A

    const unsigned long long b0 = kb_lds[0];
    const int nk = __popcll(b0) + __popcll(kb_lds[1]);
    const int NK32 = (nk + 31) >> 5;
    int rank = 0;
    if (keep) {
        rank = __popcll(bal & ((1ull << lane) - 1)) + ((wave & 1) ? __popcll(b0) : 0);
        if (wave < 2) jmap_lds[rank] = j;
    }

    // ---- softmax: 4 heads per thread-half ----
    float badd[4];
    badd[0] = bf2f((unsigned short)(braw.x & 0xffffu));
    badd[1] = bf2f((unsigned short)(braw.x >> 16));
    badd[2] = bf2f((unsigned short)(braw.y & 0xffffu));
    badd[3] = bf2f((unsigned short)(braw.y >> 16));
    float p4[4];
#pragma unroll
    for (int k = 0; k < 4; ++k) {
        float lv = __bfloat162float(lr4[k]) + badd[k];
        p4[k] = keep ? __expf(lv) : 0.f;
    }
#pragma unroll
    for (int k = 0; k < 4; ++k) {
        float v = p4[k];
        for (int off = 32; off >= 1; off >>= 1) v += __shfl_xor(v, off, 64);
        if (lane == 0) reds[wave][hbase + k] = v;
    }
    __syncthreads();                       // B
    if (keep) {
        const int pb = (tid >> 7) * 2;
#pragma unroll
        for (int k = 0; k < 4; ++k) {
            const int hh = hbase + k;
            float inv = __builtin_amdgcn_rcpf(reds[pb][hh] + reds[pb + 1][hh]);
            w_bf[hh][rank] = f2bf(p4[k] * inv);
        }
    }
    __syncthreads();                       // C

    // ---- pass 2 ----
    const int jg = tid >> 5;
    const int c0v = (tid & 31) * 4;
    const int h0v = c0v >> 4;
    const int perg = NK32 * 4;
    const float* Vs = V + (size_t)s * L * D;

    if (i > 0) {
        const int ng0 = 2 * wave;
        float rvw[2][6];
#pragma unroll
        for (int n = 0; n < 2; ++n) {
            const int c = (ng0 + n) * 16 + hA;
            float4 ra = *(const float4*)&RVW[(size_t)c * 8 + 0];
            rvw[n][0] = ra.x; rvw[n][1] = ra.y; rvw[n][2] = ra.z; rvw[n][3] = ra.w;
            rvw[n][4] = RVW[(size_t)c * 8 + 4];
            rvw[n][5] = RVW[(size_t)c * 8 + 5];
        }

        f32x4 accG[2];
#pragma unroll
        for (int n = 0; n < 2; ++n) accG[n] = (f32x4){0.f, 0.f, 0.f, 0.f};

#pragma unroll
        for (int kt = 0; kt < 4; ++kt) {
            if (kt >= NK32) break;
            s16x8 wf;
#pragma unroll
            for (int e = 0; e < 8; ++e) wf[e] = 0;
            if (hA < NH) {
                wf = *(const s16x8*)&w_bf[hA][kt * 32 + kg * 8];
                if (kt == 0 && kg == 0) wf[0] = 0;
            }
            s16x8 bfr[2];
#pragma unroll
            for (int e = 0; e < 8; ++e) {
                const int jj = jmap_lds[kt * 32 + kg * 8 + e];
                float4 fa = feat4_lds[jj + (jj >> 3)];
                float f5 = feat5_lds[jj];
#pragma unroll
                for (int n = 0; n < 2; ++n) {
                    float hv = rvw[n][5];
                    hv = fmaf(fa.x, rvw[n][0], hv);
                    hv = fmaf(fa.y, rvw[n][1], hv);
                    hv = fmaf(fa.z, rvw[n][2], hv);
                    hv = fmaf(fa.w, rvw[n][3], hv);
                    hv = fmaf(f5,  rvw[n][4], hv);
                    bfr[n][e] = (short)f2bf(gelu_sig(hv));
                }
            }
#pragma unroll
            for (int n = 0; n < 2; ++n)
                accG[n] = __builtin_amdgcn_mfma_f32_16x16x32_bf16(wf, bfr[n], accG[n], 0, 0, 0);
        }

        // ---- a1 over compacted keys (8 groups) ----
        float a1a[4] = {0.f, 0.f, 0.f, 0.f};
        for (int r = 0; r < perg; ++r) {
            const int jt = jg * perg + r;
            const int jr = jmap_lds[jt];
            float4 vcur = *(const float4*)&Vs[(size_t)jr * D + c0v];
            const float wj = bf2f(w_bf[h0v][jt]);
            a1a[0] = fmaf(wj, vcur.x, a1a[0]);
            a1a[1] = fmaf(wj, vcur.y, a1a[1]);
            a1a[2] = fmaf(wj, vcur.z, a1a[2]);
            a1a[3] = fmaf(wj, vcur.w, a1a[3]);
        }
        *(float4*)&a1_part[jg][c0v] = make_float4(a1a[0], a1a[1], a1a[2], a1a[3]);

        if (lane < 32) {
#pragma unroll
            for (int n = 0; n < 2; ++n)
#pragma unroll
                for (int r = 0; r < 4; ++r)
                    gs_bf[(lane >> 4) * 4 + r][(ng0 + n) * 16 + hA] = f2bf(accG[n][r]);
        }
        __syncthreads();

        // ---- a2 = GS @ Wv2 via MFMA (2 col-frags per wave) ----
        f32x4 acc2[2];
#pragma unroll
        for (int n = 0; n < 2; ++n) acc2[n] = (f32x4){0.f, 0.f, 0.f, 0.f};
#pragma unroll
        for (int kt = 0; kt < 4; ++kt) {
            s16x8 gf;
#pragma unroll
            for (int e = 0; e < 8; ++e) gf[e] = 0;
            if (hA < NH)
                gf = *(const s16x8*)&gs_bf[hA][kt * 32 + kg * 8];
#pragma unroll
            for (int n = 0; n < 2; ++n) {
                const int f = kt * 8 + ng0 + n;
                s16x8 bw = *(const s16x8*)&WV2F[((size_t)f * 64 + lane) * 8];
                acc2[n] = __builtin_amdgcn_mfma_f32_16x16x32_bf16(gf, bw, acc2[n], 0, 0, 0);
            }
        }
#pragma unroll
        for (int n = 0; n < 2; ++n) {
            const int f = ng0 + n;
            if (kg == (f >> 2)) a2_lds[f * 16 + hA] = acc2[n][f & 3];
        }
        __syncthreads();

        if (tid < 128) {
            float a1f = a1_part[0][tid] + a1_part[1][tid] + a1_part[2][tid] + a1_part[3][tid]
                      + a1_part[4][tid] + a1_part[5][tid] + a1_part[6][tid] + a1_part[7][tid];
            const float S1 = 1.0f - bf2f(w_bf[tid >> 4][0]);
            const size_t o = (size_t)s * TT * D + (size_t)(i - 1) * D + tid;
            out[o] = a1f + a2_lds[tid] + S1 * bv2[tid] + padded[o];
        }
    } else {
        // ---- cls row: a2 == 0; V-reduce + layernorm ----
        float a1a[4] = {0.f, 0.f, 0.f, 0.f};
        for (int r = 0; r < perg; ++r) {
            const int jt = jg * perg + r;
            const int jr = jmap_lds[jt];
            float4 vcur = *(const float4*)&Vs[(size_t)jr * D + c0v];
            const float wj = bf2f(w_bf[h0v][jt]);
            a1a[0] = fmaf(wj, vcur.x, a1a[0]);
            a1a[1] = fmaf(wj, vcur.y, a1a[1]);
            a1a[2] = fmaf(wj, vcur.z, a1a[2]);
            a1a[3] = fmaf(wj, vcur.w, a1a[3]);
        }
        *(float4*)&a1_part[jg][c0v] = make_float4(a1a[0], a1a[1], a1a[2], a1a[3]);
        __syncthreads();

        float st = 0.f;
        if (tid < 128) {
            float a1f = a1_part[0][tid] + a1_part[1][tid] + a1_part[2][tid] + a1_part[3][tid]
                      + a1_part[4][tid] + a1_part[5][tid] + a1_part[6][tid] + a1_part[7][tid];
            st = a1f + tok[tid];
            float sum = st, sum2 = st * st;
            for (int off = 32; off >= 1; off >>= 1) {
                sum += __shfl_xor(sum, off, 64);
                sum2 += __shfl_xor(sum2, off, 64);
            }
            if (lane == 0) { red2[wave][0] = sum; red2[wave][1] = sum2; }
        }
        __syncthreads();
        if (tid < 128) {
            float sum = red2[0][0] + red2[1][0];
            float sum2 = red2[0][1] + red2[1][1];
            const float mu = sum * (1.0f / 128.0f);
            const float var = sum2 * (1.0f / 128.0f) - mu * mu;
            const float y = (st - mu) * rsqrtf(var + 1e-5f) * gamma[tid] + beta[tid];
            out[(size_t)BN * TT * D + (size_t)s * D + tid] = y;
        }
    }
}

extern "C" void kernel_launch(void* const* d_in, const int* in_sizes, int n_in,
                              void* d_out, int out_size, void* d_ws, size_t ws_size,
                              hipStream_t stream) {
    const float* padded = (const float*)d_in[0];
    const int*   masks  = (const int*)d_in[1];
    const float* pos3d  = (const float*)d_in[2];
    const float* Wq = (const float*)d_in[3];
    const float* bq = (const float*)d_in[4];
    const float* Wk = (const float*)d_in[5];
    const float* bk = (const float*)d_in[6];
    const float* Wv = (const float*)d_in[7];
    const float* bv = (const float*)d_in[8];
    const float* gamma = (const float*)d_in[9];
    const float* beta  = (const float*)d_in[10];
    const float* tok   = (const float*)d_in[11];
    const float* Wb1 = (const float*)d_in[12];
    const float* bb1 = (const float*)d_in[13];
    const float* Wb2 = (const float*)d_in[14];
    const float* bb2 = (const float*)d_in[15];
    const float* Wv1 = (const float*)d_in[16];
    const float* bv1 = (const float*)d_in[17];
    const float* Wv2 = (const float*)d_in[18];
    const float* bv2 = (const float*)d_in[19];
    float* out = (float*)d_out;

    float* Q  = (float*)d_ws;
    float* K  = Q + (size_t)BN * L * D;
    float* Vw = K + (size_t)BN * L * D;
    __hip_bfloat16* LW = (__hip_bfloat16*)(Vw + (size_t)BN * L * D);
    unsigned short* BIAS = (unsigned short*)(LW + (size_t)BN * NH * L * L);
    float* RVW = (float*)(BIAS + (size_t)BN * L * L * NH);
    unsigned short* WV2F = (unsigned short*)(RVW + 128 * 8);

    qkv_bias_kernel<<<dim3(384 + BN * 64), 256, 0, stream>>>(
        padded, tok, Wq, bq, Wk, bk, Wv, bv, Wb1, bb1, Wb2, bb2, Wv1, bv1, Wv2,
        masks, pos3d, Q, K, Vw, RVW, WV2F, BIAS);
    logits_kernel<<<dim3(BN * NH), 256, 0, stream>>>(Q, K, LW);
    attn_kernel<<<dim3(L, BN), 256, 0, stream>>>(padded, masks, pos3d, gamma, beta, tok,
                                                 RVW, WV2F, bv2,
                                                 Vw, LW, BIAS, out);
}